// Round 6
// baseline (130149.561 us; speedup 1.0000x reference)
//
#include <hip/hip_runtime.h>
#include <cstdio>

// ---------------- dims ----------------
static constexpr int cB = 32, cTENC = 256, cENCD = 512, cTDEC = 500, cMEL = 80,
    cNSTEP = 250, cPRE = 256, cAD = 128, cAR = 1024, cDR = 1024, cFLT = 32,
    cKSZ = 31, cPADC = 15, cNG = 4096;
static constexpr int cKA = cPRE + cENCD + cAR;   // 1792 : [x | ctx | h_a]
static constexpr int cKD = cAR + cENCD + cDR;    // 2560 : [h_a | ctx | dec_h]
static constexpr int cKM = cDR + cENCD;          // 1536 : [dec_h | ctx]
static constexpr int cNMP = 192;                 // padded 161 (160 mel + 1 stop)
static constexpr int cNSA = 14;                  // attn k-splits (span 128)
static constexpr int cNSD = 16;                  // dec  k-splits (span 160)
static constexpr int cRDA = 128;                 // attn LDS-resident rows (all)
static constexpr int cRDD = 132;                 // dec LDS-resident rows (of 160)
static constexpr int cDYN = 158208;              // dec: 132*1024 + 160*36*4

typedef unsigned short ushortT;
typedef unsigned int uintT;
typedef unsigned long long ullT;

// ---------------- output layout (floats) ----------------
static constexpr size_t MEL_OFF = 0;
static constexpr size_t STOP_OFF = (size_t)cB * cTDEC * cMEL;      // 1,280,000
static constexpr size_t ATT_OFF = STOP_OFF + (size_t)cB * cTDEC;   // 1,296,000

// ---------------- workspace layout (float units) ----------------
static constexpr size_t WS_WATB = 0;                                   // us[1792][4096]
static constexpr size_t WS_WDTB = WS_WATB + (size_t)cKA * cNG / 2;     // us[2560][4096]
static constexpr size_t WS_WMT  = WS_WDTB + (size_t)cKD * cNG / 2;     // f[1536][192]
static constexpr size_t WS_WQT  = WS_WMT  + (size_t)cKM * cNMP;        // f[1024][128]
static constexpr size_t WS_WMTR = WS_WQT  + (size_t)cAR * cAD;         // f[512][128]
static constexpr size_t WS_PM   = WS_WMTR + (size_t)cENCD * cAD;       // f[32][256][128]
static constexpr size_t WS_XPRE = WS_PM   + (size_t)cB * cTENC * cAD;  // f[250][32][256]
static constexpr size_t WS_XA   = WS_XPRE + (size_t)cNSTEP * cPRE * cB;// f[2][32][1792]
static constexpr size_t WS_XD   = WS_XA   + (size_t)2 * cB * cKA;      // f[32][2560]
static constexpr size_t WS_CA   = WS_XD   + (size_t)cB * cKD;          // f[8][32][128] private
static constexpr size_t WS_CD   = WS_CA   + (size_t)8 * cB * 128;      // f[8][32][128] private
static constexpr size_t WS_CUMP = WS_CD   + (size_t)8 * cB * 128;      // f[32][256] private
static constexpr size_t WS_PQP  = WS_CUMP + (size_t)cB * cTENC;        // f[8][32][128] (sc)
static constexpr size_t WS_CTR  = WS_PQP  + (size_t)8 * cB * 128;      // u32[128]
static constexpr size_t WS_FLG  = WS_CTR  + 128;                       // u32[64]
static constexpr size_t WS_SLOT = WS_FLG  + 64;                        // u32[64]
static constexpr size_t WS_GA   = WS_SLOT + 64;                        // f[2][8][14][32][512]
static constexpr size_t WS_GD   = WS_GA   + (size_t)2 * 8 * cNSA * cB * 512;
static constexpr size_t WS_PROJ = WS_GD   + (size_t)2 * 8 * cNSD * cB * 512; // f[250][32][1536]
static constexpr size_t WS_TOTAL = WS_PROJ + (size_t)cNSTEP * cB * cKM;
// X1 (prenet intermediate) aliases GA region: used only pre-loop.
static constexpr size_t WS_X1   = WS_GA;                               // f[250][32][256]

struct Args {
  const float *enc, *inputs;
  const int *mlen;
  const float *W1, *b1, *W2, *b2, *Wm;
  const float *Wih_a, *Whh_a, *bih_a, *bhh_a;
  const float *Wq, *conv_w, *conv_b, *WL, *v;
  const float *Wih_d, *Whh_d, *bih_d, *bhh_d;
  const float *Wmel, *bmel, *Wstop, *bstop;
  float *out;
  float *ws;
};

struct AttnSh {
  float pq[cAD];
  float cumext[cTENC + 2 * cPADC];
  float eparts[2][cTENC];
  float e[cTENC];
  float sred[16];
  float loc[cFLT * 257];
  float wl[cAD * 33];
  float cw[cFLT * cKSZ];
  float vv[cAD];
};

// ---------- agent-scope (cross-XCD, via L3) access ----------
__device__ __forceinline__ float ld_sc(const float* p) {
  return __hip_atomic_load(p, __ATOMIC_RELAXED, __HIP_MEMORY_SCOPE_AGENT);
}
__device__ __forceinline__ void st_sc(float* p, float v) {
  __hip_atomic_store(p, v, __ATOMIC_RELAXED, __HIP_MEMORY_SCOPE_AGENT);
}
__device__ __forceinline__ float2 ld_sc2(const float2* p) {
  ullT u = __hip_atomic_load((const ullT*)p, __ATOMIC_RELAXED, __HIP_MEMORY_SCOPE_AGENT);
  float2 r;
  r.x = __uint_as_float((uintT)u);
  r.y = __uint_as_float((uintT)(u >> 32));
  return r;
}
__device__ __forceinline__ void st_sc2(float2* p, float x, float y) {
  ullT u = (ullT)__float_as_uint(x) | ((ullT)__float_as_uint(y) << 32);
  __hip_atomic_store((ullT*)p, u, __ATOMIC_RELAXED, __HIP_MEMORY_SCOPE_AGENT);
}
__device__ __forceinline__ uintT ld_scu(const uintT* p) {
  return __hip_atomic_load(p, __ATOMIC_RELAXED, __HIP_MEMORY_SCOPE_AGENT);
}
__device__ __forceinline__ void st_scu(uintT* p, uintT v) {
  __hip_atomic_store(p, v, __ATOMIC_RELAXED, __HIP_MEMORY_SCOPE_AGENT);
}

// Distributed monotonic grid barrier: 8 counters, 64B apart.
__device__ __forceinline__ void gbar(uintT* ctrs, uintT ph) {
  __syncthreads();
  if (threadIdx.x == 0)
    __hip_atomic_fetch_add(ctrs + (blockIdx.x & 7) * 16, 1u,
                           __ATOMIC_RELAXED, __HIP_MEMORY_SCOPE_AGENT);
  if (threadIdx.x < 8) {
    const uintT target = ph * 32u;
    while (ld_scu(ctrs + threadIdx.x * 16) < target)
      __builtin_amdgcn_s_sleep(2);
  }
  __syncthreads();
}

__device__ __forceinline__ float sigm_f(float x) { return 1.f / (1.f + __expf(-x)); }
__device__ __forceinline__ float tanh_f(float x) {
  float e = __expf(2.f * x);
  return 1.f - 2.f / (e + 1.f);
}

__device__ __forceinline__ void fma8x4(float (&acc)[8][4], const uint4 w, const float4 x4) {
  float wf[8];
  wf[0] = __uint_as_float(w.x << 16);
  wf[1] = __uint_as_float(w.x & 0xFFFF0000u);
  wf[2] = __uint_as_float(w.y << 16);
  wf[3] = __uint_as_float(w.y & 0xFFFF0000u);
  wf[4] = __uint_as_float(w.z << 16);
  wf[5] = __uint_as_float(w.z & 0xFFFF0000u);
  wf[6] = __uint_as_float(w.w << 16);
  wf[7] = __uint_as_float(w.w & 0xFFFF0000u);
  const float xv[4] = {x4.x, x4.y, x4.z, x4.w};
#pragma unroll
  for (int c = 0; c < 8; ++c)
#pragma unroll
    for (int j = 0; j < 4; ++j) acc[c][j] = fmaf(wf[c], xv[j], acc[c][j]);
}

// One-time weight preload into LDS, gathering the XCD's 4 gate-strips.
// wsrc = WT + k0*cNG + xcd*128. LDS layout: [row][64 uint4] (packed 512 cols).
static __device__ void preload2(uint4* dst, const ushortT* wsrc, int rows) {
  for (int i = threadIdx.x; i < rows * 64; i += 512) {
    const int r = i >> 6, u = i & 63;
    const int strip = u >> 4, within = (u & 15) * 8;
    dst[i] = *(const uint4*)(wsrc + (size_t)r * cNG + strip * 1024 + within);
  }
}

// Batch-32 GEMV partial: LDS weights (+ optional streamed tail rows).
// x layout [b][K]; partials -> partbase[(slot*32+b)*512 + j] (plain, XCD-local).
template <int KSPAN, int RD, int NS>
static __device__ void gemv2(const ushortT* __restrict__ wlds,
                             const ushortT* __restrict__ wstream,
                             const float* __restrict__ xb, int xstride,
                             float* __restrict__ partbase, int slot,
                             float* __restrict__ xs) {
  const int tid = threadIdx.x;
  {
    const int b = tid >> 4, kt = tid & 15;
    const float* src = xb + (size_t)b * xstride;
    for (int kp = kt; kp < KSPAN / 2; kp += 16) {
      float2 u = ld_sc2((const float2*)(src + 2 * kp));
      xs[(2 * kp) * 36 + b] = u.x;
      xs[(2 * kp + 1) * 36 + b] = u.y;
    }
  }
  __syncthreads();
  const int cq = tid & 63, bq = tid >> 6;
  const uint4* wl4 = (const uint4*)wlds + cq;
  const float* xp = xs + bq * 4;
  float acc[8][4];
#pragma unroll
  for (int c = 0; c < 8; ++c)
#pragma unroll
    for (int j = 0; j < 4; ++j) acc[c][j] = 0.f;
#pragma unroll 4
  for (int k = 0; k < RD; ++k) {
    const uint4 w = wl4[(size_t)k * 64];
    const float4 x4 = *(const float4*)(xp + k * 36);
    fma8x4(acc, w, x4);
  }
  if (RD < KSPAN) {
    const int strip = cq >> 4, within = (cq & 15) * 8;
    const ushortT* wg2 = wstream + strip * 1024 + within;
#pragma unroll 4
    for (int k = RD; k < KSPAN; ++k) {
      const uint4 w = *(const uint4*)(wg2 + (size_t)k * cNG);
      const float4 x4 = *(const float4*)(xp + k * 36);
      fma8x4(acc, w, x4);
    }
  }
  const int b0 = bq * 4;
#pragma unroll
  for (int j = 0; j < 4; ++j) {
    float* dst = partbase + (((size_t)slot * cB + (b0 + j)) * 512 + cq * 8);
    float4 o0, o1;
    o0.x = acc[0][j]; o0.y = acc[1][j]; o0.z = acc[2][j]; o0.w = acc[3][j];
    o1.x = acc[4][j]; o1.y = acc[5][j]; o1.z = acc[6][j]; o1.w = acc[7][j];
    *(float4*)dst = o0;
    *(float4*)(dst + 4) = o1;
  }
  __syncthreads();
}

// attn-LSTM cell for this XCD's 128-h block (slot 0). Publishes h (sc), pq_part (sc), flag.
static __device__ void attn_cell(const Args& a, float* ws, int xcd, int t, int p,
                                 float* __restrict__ xa2, float* __restrict__ hs) {
  const int tid = threadIdx.x;
  const int b = tid >> 4, h0 = (tid & 15) * 8;
  const float* base = ws + WS_GA + ((size_t)p * 8 + xcd) * (cNSA * cB * 512);
  float g4[4][8];
#pragma unroll
  for (int g = 0; g < 4; ++g) {
    const int n = g * 1024 + xcd * 128 + h0;
#pragma unroll
    for (int e = 0; e < 8; ++e) g4[g][e] = a.bih_a[n + e] + a.bhh_a[n + e];
  }
  for (int s = 0; s < cNSA; ++s) {
    const float* pb = base + ((size_t)s * cB + b) * 512;
#pragma unroll
    for (int g = 0; g < 4; ++g) {
      const float4 a0 = *(const float4*)(pb + g * 128 + h0);
      const float4 a1 = *(const float4*)(pb + g * 128 + h0 + 4);
      g4[g][0] += a0.x; g4[g][1] += a0.y; g4[g][2] += a0.z; g4[g][3] += a0.w;
      g4[g][4] += a1.x; g4[g][5] += a1.y; g4[g][6] += a1.z; g4[g][7] += a1.w;
    }
  }
  float* cp = ws + WS_CA + ((size_t)xcd * cB + b) * 128 + h0;   // private, plain
  float hn[8];
#pragma unroll
  for (int e = 0; e < 8; ++e) {
    const float cn = sigm_f(g4[1][e]) * cp[e] + sigm_f(g4[0][e]) * tanh_f(g4[2][e]);
    hn[e] = sigm_f(g4[3][e]) * tanh_f(cn);
    cp[e] = cn;
  }
  float* xd = ws + WS_XD + (size_t)b * cKD + xcd * 128 + h0;
  float* xa = xa2 + (size_t)b * cKA + (cPRE + cENCD) + xcd * 128 + h0;
#pragma unroll
  for (int e = 0; e < 8; e += 2) {
    st_sc2((float2*)(xd + e), hn[e], hn[e + 1]);
    st_sc2((float2*)(xa + e), hn[e], hn[e + 1]);
  }
#pragma unroll
  for (int e = 0; e < 8; ++e) hs[b * 132 + h0 + e] = hn[e];
  __syncthreads();
  // pq partial: pqp[xcd][b][d] = sum_h hn[b][h] * WqT[xcd*128+h][d]
  {
    const int d = tid & 127, bg = tid >> 7;
    const float* wqt = ws + WS_WQT + (size_t)(xcd * 128) * cAD + d;
    for (int bb = bg * 8; bb < bg * 8 + 8; ++bb) {
      float acc = 0.f;
      for (int h = 0; h < 128; ++h) acc = fmaf(hs[bb * 132 + h], wqt[(size_t)h * cAD], acc);
      st_sc(ws + WS_PQP + ((size_t)xcd * cB + bb) * cAD + d, acc);
    }
  }
  __syncthreads();
  if (tid == 0) st_scu((uintT*)(ws + WS_FLG) + xcd * 8, (uintT)(t + 1));
}

// dec-LSTM cell for this XCD's 128-h block (slot 1), step s.
static __device__ void dec_cell2(const Args& a, float* ws, int xcd, int s, int p) {
  const int tid = threadIdx.x;
  const int b = tid >> 4, h0 = (tid & 15) * 8;
  const float* base = ws + WS_GD + ((size_t)p * 8 + xcd) * (cNSD * cB * 512);
  float g4[4][8];
#pragma unroll
  for (int g = 0; g < 4; ++g) {
    const int n = g * 1024 + xcd * 128 + h0;
#pragma unroll
    for (int e = 0; e < 8; ++e) g4[g][e] = a.bih_d[n + e] + a.bhh_d[n + e];
  }
  for (int sl = 0; sl < cNSD; ++sl) {
    const float* pb = base + ((size_t)sl * cB + b) * 512;
#pragma unroll
    for (int g = 0; g < 4; ++g) {
      const float4 a0 = *(const float4*)(pb + g * 128 + h0);
      const float4 a1 = *(const float4*)(pb + g * 128 + h0 + 4);
      g4[g][0] += a0.x; g4[g][1] += a0.y; g4[g][2] += a0.z; g4[g][3] += a0.w;
      g4[g][4] += a1.x; g4[g][5] += a1.y; g4[g][6] += a1.z; g4[g][7] += a1.w;
    }
  }
  float* cp = ws + WS_CD + ((size_t)xcd * cB + b) * 128 + h0;
  float hn[8];
#pragma unroll
  for (int e = 0; e < 8; ++e) {
    const float cn = sigm_f(g4[1][e]) * cp[e] + sigm_f(g4[0][e]) * tanh_f(g4[2][e]);
    hn[e] = sigm_f(g4[3][e]) * tanh_f(cn);
    cp[e] = cn;
  }
  float* xd = ws + WS_XD + (size_t)b * cKD + (cAR + cENCD) + xcd * 128 + h0;
  float* pj = ws + WS_PROJ + ((size_t)s * cB + b) * cKM + xcd * 128 + h0;
#pragma unroll
  for (int e = 0; e < 8; e += 2) {
    st_sc2((float2*)(xd + e), hn[e], hn[e + 1]);
    st_sc2((float2*)(pj + e), hn[e], hn[e + 1]);
  }
}

// Attention for batch b at step t (slots 30/31).
static __device__ void attention(const Args& a, float* ws, int b, int t,
                                 float* __restrict__ xa2, AttnSh& sh) {
  const int tid = threadIdx.x;
  // wait for all XCDs' pq parts
  if (tid < 8) {
    const uintT* flg = (const uintT*)(ws + WS_FLG) + tid * 8;
    while (ld_scu(flg) < (uintT)(t + 1)) __builtin_amdgcn_s_sleep(1);
  }
  __syncthreads();
  if (tid < cAD) {
    float s = 0.f;
#pragma unroll
    for (int x = 0; x < 8; ++x) s += ld_sc(ws + WS_PQP + ((size_t)x * cB + b) * cAD + tid);
    sh.pq[tid] = s;
  }
  if (tid < cTENC) sh.cumext[cPADC + tid] = ws[WS_CUMP + (size_t)b * cTENC + tid];
  if (tid >= cTENC && tid < cTENC + 30) {
    const int q = tid - cTENC;
    sh.cumext[q < cPADC ? q : cTENC + q] = 0.f;
  }
  for (int i = tid; i < cAD * 33; i += 512) {
    const int dd = i / 33, f = i - dd * 33;
    sh.wl[i] = (f < cFLT) ? a.WL[dd * cFLT + f] : 0.f;
  }
  for (int i = tid; i < cFLT * cKSZ; i += 512) sh.cw[i] = a.conv_w[i];
  if (tid < cAD) sh.vv[tid] = a.v[tid];
  __syncthreads();
  // conv31 over cum
  for (int i = tid; i < cFLT * cTENC; i += 512) {
    const int f = i >> 8, te = i & 255;
    float s = a.conv_b[f];
#pragma unroll
    for (int j = 0; j < cKSZ; ++j) s = fmaf(sh.cumext[te + j], sh.cw[f * cKSZ + j], s);
    sh.loc[f * 257 + te] = s;
  }
  __syncthreads();
  // energies
  {
    const int d = tid & 127, tq = tid >> 7, wv = tid >> 6;
    float wlr[cFLT];
#pragma unroll
    for (int f = 0; f < cFLT; ++f) wlr[f] = sh.wl[d * 33 + f];
    const float pqd = sh.pq[d], vd = sh.vv[d];
    const float* pmb = ws + WS_PM + (size_t)b * cTENC * cAD;
    for (int tt = 0; tt < cTENC / 4; ++tt) {
      const int te = tt * 4 + tq;
      float s = pqd + pmb[(size_t)te * cAD + d];
#pragma unroll
      for (int f = 0; f < cFLT; ++f) s = fmaf(sh.loc[f * 257 + te], wlr[f], s);
      float pv = tanh_f(s) * vd;
#pragma unroll
      for (int off = 32; off > 0; off >>= 1) pv += __shfl_xor(pv, off, 64);
      if ((tid & 63) == 0) sh.eparts[wv & 1][te] = pv;
    }
  }
  __syncthreads();
  // mask + softmax over 256
  const int mlen = a.mlen[b];
  if (tid < cTENC) {
    float ev = sh.eparts[0][tid] + sh.eparts[1][tid];
    if (tid >= mlen) ev = -1e9f;
    sh.e[tid] = ev;
  }
  __syncthreads();
  const int wv = tid >> 6;
  {
    float xv = sh.e[tid & 255];
#pragma unroll
    for (int off = 32; off > 0; off >>= 1) xv = fmaxf(xv, __shfl_xor(xv, off, 64));
    if ((tid & 63) == 0) sh.sred[wv] = xv;
  }
  __syncthreads();
  float m = sh.sred[0];
#pragma unroll
  for (int i = 1; i < 8; ++i) m = fmaxf(m, sh.sred[i]);
  const float pex = (tid < cTENC) ? __expf(sh.e[tid] - m) : 0.f;
  {
    float sv = pex;
#pragma unroll
    for (int off = 32; off > 0; off >>= 1) sv += __shfl_xor(sv, off, 64);
    if ((tid & 63) == 0) sh.sred[8 + wv] = sv;
  }
  __syncthreads();
  float ssum = 0.f;
#pragma unroll
  for (int i = 0; i < 8; ++i) ssum += sh.sred[8 + i];
  const float rs = 1.f / ssum;
  if (tid < cTENC) {
    const float al = pex * rs;
    sh.e[tid] = al;
    a.out[ATT_OFF + ((size_t)b * cNSTEP + t) * cTENC + tid] = al;
    ws[WS_CUMP + (size_t)b * cTENC + tid] = sh.cumext[cPADC + tid] + al;  // private
  }
  __syncthreads();
  // ctx = align @ encoder_outputs[b]
  {
    const int k = tid;   // 512 = ENCD
    float acc = 0.f;
    const float* encb = a.enc + (size_t)b * cTENC * cENCD + k;
    for (int te = 0; te < cTENC; ++te) acc = fmaf(sh.e[te], encb[(size_t)te * cENCD], acc);
    st_sc(xa2 + (size_t)b * cKA + cPRE + k, acc);
    st_sc(ws + WS_XD + (size_t)b * cKD + cAR + k, acc);
    st_sc(ws + WS_PROJ + ((size_t)t * cB + b) * cKM + cDR + k, acc);
  }
  __syncthreads();
}

// Post-loop batched mel/stop projection (plain loads; PROJ [t][b][k]).
static __device__ void mel_proj(const Args& a, float* ws, float* melred) {
  const int tid = threadIdx.x;
  const int c = tid & 255, sub = tid >> 8;
  for (int t = blockIdx.x; t < cNSTEP; t += gridDim.x) {
    float acc[cB];
#pragma unroll
    for (int b = 0; b < cB; ++b) acc[b] = 0.f;
    if (c < 161) {
      const float* wmt = ws + WS_WMT;
      const float* xr0 = ws + WS_PROJ + (size_t)t * cB * cKM;
      const int k0 = sub * 768;
      for (int k = k0; k < k0 + 768; ++k) {
        const float w = wmt[(size_t)k * cNMP + c];
#pragma unroll
        for (int b = 0; b < cB; ++b) acc[b] = fmaf(w, xr0[(size_t)b * cKM + k], acc[b]);
      }
    }
    __syncthreads();
    if (sub == 1 && c < 161) {
#pragma unroll
      for (int b = 0; b < cB; ++b) melred[b * 164 + c] = acc[b];
    }
    __syncthreads();
    if (sub == 0 && c < 161) {
      if (c < 160) {
        const int fr = c / 80, mm = c % 80;
        const float bm = a.bmel[c];
#pragma unroll
        for (int b = 0; b < cB; ++b) {
          const float val = acc[b] + melred[b * 164 + c] + bm;
          a.out[MEL_OFF + ((size_t)b * cTDEC + (2 * t + fr)) * cMEL + mm] = val;
        }
      } else {
        const float bs = a.bstop[0];
#pragma unroll
        for (int b = 0; b < cB; ++b) {
          const float sp = sigm_f(acc[b] + melred[b * 164 + c] + bs);
          a.out[STOP_OFF + (size_t)b * cTDEC + 2 * t] = sp;
          a.out[STOP_OFF + (size_t)b * cTDEC + 2 * t + 1] = sp;
        }
      }
    }
    __syncthreads();
  }
}

// ---------------- setup kernels ----------------
__device__ __forceinline__ ushortT f2b(float f) {
  const uintT u = __float_as_uint(f);
  return (ushortT)((u + 0x7FFFu + ((u >> 16) & 1u)) >> 16);   // RNE
}

__global__ void k_transpose(const float* __restrict__ src, float* __restrict__ dst,
                            int N, int K, int dpitch) {
  __shared__ float tile[64][65];
  const int tkn = K >> 6;
  const int tk = blockIdx.x % tkn, tn = blockIdx.x / tkn;
  const int c = threadIdx.x & 63, r4 = threadIdx.x >> 6;
  const int n0 = tn << 6, k0 = tk << 6;
#pragma unroll
  for (int rr = 0; rr < 16; ++rr) {
    const int r = r4 * 16 + rr;
    tile[r][c] = src[(size_t)(n0 + r) * K + k0 + c];
  }
  __syncthreads();
#pragma unroll
  for (int rr = 0; rr < 16; ++rr) {
    const int r = r4 * 16 + rr;
    dst[(size_t)(k0 + r) * dpitch + n0 + c] = tile[c][r];
  }
}

__global__ void k_transpose_b16(const float* __restrict__ src, ushortT* __restrict__ dst,
                                int N, int K, int dpitch) {
  __shared__ float tile[64][65];
  const int tkn = K >> 6;
  const int tk = blockIdx.x % tkn, tn = blockIdx.x / tkn;
  const int c = threadIdx.x & 63, r4 = threadIdx.x >> 6;
  const int n0 = tn << 6, k0 = tk << 6;
#pragma unroll
  for (int rr = 0; rr < 16; ++rr) {
    const int r = r4 * 16 + rr;
    tile[r][c] = src[(size_t)(n0 + r) * K + k0 + c];
  }
  __syncthreads();
#pragma unroll
  for (int rr = 0; rr < 16; ++rr) {
    const int r = r4 * 16 + rr;
    dst[(size_t)(k0 + r) * dpitch + n0 + c] = f2b(tile[c][r]);
  }
}

__global__ void k_prep_small(Args a) {
  const size_t i = (size_t)blockIdx.x * blockDim.x + threadIdx.x;
  if (i < 256) ((uintT*)(a.ws + WS_CTR))[i] = 0u;   // CTR(128)+FLG(64)+SLOT(64)
  if (i >= (size_t)cKM * cNMP) return;
  const int k = (int)(i / cNMP), c = (int)(i % cNMP);
  a.ws[WS_WMT + i] = (c < 160) ? a.Wmel[(size_t)c * cKM + k]
                               : (c == 160 ? a.Wstop[k] : 0.f);
}

__global__ void k_prenet1(Args a) {
  const size_t i = (size_t)blockIdx.x * blockDim.x + threadIdx.x;
  if (i >= (size_t)cNSTEP * cB * cPRE) return;
  const int j = i & 255, b = (i >> 8) & 31, n = (int)(i >> 13);
  float acc = a.b1[j];
  if (n > 0) {
    const float* fr = a.inputs + ((size_t)b * cTDEC + (2 * n - 1)) * cMEL;
    for (int k = 0; k < cMEL; ++k) acc = fmaf(fr[k], a.W1[j * cMEL + k], acc);
  }
  a.ws[WS_X1 + i] = fmaxf(acc, 0.f);   // [n][b][j]
}

__global__ void k_prenet2(Args a) {
  const size_t i = (size_t)blockIdx.x * blockDim.x + threadIdx.x;
  if (i >= (size_t)cNSTEP * cPRE * cB) return;
  const int j = i & 255, b = (i >> 8) & 31, n = (int)(i >> 13);
  float acc = a.b2[j];
  const float* x1 = a.ws + WS_X1 + ((size_t)n * cB + b) * cPRE;
  for (int k = 0; k < cPRE; ++k) acc = fmaf(x1[k], a.W2[j * cPRE + k], acc);
  a.ws[WS_XPRE + ((size_t)n * cB + b) * cPRE + j] = fmaxf(acc, 0.f);   // [n][b][j]
}

__global__ void k_pm(Args a) {
  const size_t i = (size_t)blockIdx.x * blockDim.x + threadIdx.x;
  if (i >= (size_t)cB * cTENC * cAD) return;
  const int d = i & 127, tt = (i >> 7) & 255, b = (int)(i >> 15);
  float acc = 0.f;
  const float* er = a.enc + ((size_t)b * cTENC + tt) * cENCD;
  const float* wt = a.ws + WS_WMTR;
  for (int k = 0; k < cENCD; ++k) acc = fmaf(er[k], wt[(size_t)k * cAD + d], acc);
  a.ws[WS_PM + i] = acc;
}

// ---------------- persistent cooperative loop ----------------
// Roles per XCD (32 WGs, dense slots via XCC_ID + atomicAdd):
//   PhA: slot 0-13 attn GEMV(t) k-split; slot 14-29 dec GEMV(t-1) k-split.
//   PhB: slot 0 attn-cell(t)+pq+flag; slot 1 dec-cell(t-1); slot 2 x-copy(t+1);
//        slot 30/31 attention (2 batches each, flag-gated).
// Partials: plain stores/loads, XCD-local, parity double-buffered.
__global__ void __launch_bounds__(512, 1) k_loop(Args a) {
  extern __shared__ char dyn[];
  float* ws = a.ws;
  uintT* ctrs = (uintT*)(ws + WS_CTR);
  const int tid = threadIdx.x;

  __shared__ int s_xcd, s_slot;
  if (tid == 0) {
    const int x = (int)(__builtin_amdgcn_s_getreg((31 << 11) | 20) & 7);  // HW_REG_XCC_ID
    const uintT sl = __hip_atomic_fetch_add((uintT*)(ws + WS_SLOT) + x * 8, 1u,
                                            __ATOMIC_RELAXED, __HIP_MEMORY_SCOPE_AGENT);
    s_xcd = x;
    s_slot = (int)sl;
  }
  __syncthreads();
  const int xcd = s_xcd, slot = s_slot;
  uintT ph = 0;

  const ushortT* watb = (const ushortT*)(ws + WS_WATB);
  const ushortT* wdtb = (const ushortT*)(ws + WS_WDTB);
  ushortT* wlds = (ushortT*)dyn;
  float* xsA = (float*)(dyn + 131072);
  float* xsD = (float*)(dyn + 135168);
  float* hs = (float*)(dyn + 131072);     // slot0 PhB, reuses xsA space
  AttnSh* at = (AttnSh*)dyn;
  float* melred = (float*)dyn;

  const int k0A = slot * 128;
  const int sD = slot - 14, k0D = sD * 160;
  const ushortT* wstrD = wdtb + (size_t)k0D * cNG + xcd * 128;

  // ---- one-time preload + init ----
  if (slot < cNSA) {
    preload2((uint4*)wlds, watb + (size_t)k0A * cNG + xcd * 128, cRDA);
  } else if (slot < cNSA + cNSD) {
    preload2((uint4*)wlds, wstrD, cRDD);
  }
  if (slot == 0) {
    float* c = ws + WS_CA + (size_t)xcd * cB * 128;
    for (int i = tid; i < cB * 128; i += 512) c[i] = 0.f;
  } else if (slot == 1) {
    float* c = ws + WS_CD + (size_t)xcd * cB * 128;
    for (int i = tid; i < cB * 128; i += 512) c[i] = 0.f;
  } else if (slot == 2) {
    for (int i = tid; i < 1024; i += 512) {   // x0 for 4 batches
      const int b = xcd * 4 + (i >> 8), j = i & 255;
      st_sc(ws + WS_XA + (size_t)b * cKA + j, ws[WS_XPRE + (size_t)b * cPRE + j]);
    }
  } else if (slot == 30 || slot == 31) {
    const int b0 = xcd * 4 + (slot - 30) * 2;
    for (int i = tid; i < 512; i += 512)
      ws[WS_CUMP + (size_t)b0 * cTENC + i] = 0.f;
  }
  {
    const int g = xcd * 32 + (slot < 32 ? slot : 31);
    const size_t idx = (size_t)g * 512 + tid;
    if (idx < 49152) {                          // XA[0] ctx+h zero
      const int b = (int)(idx / 1536), j = (int)(idx % 1536);
      st_sc(ws + WS_XA + (size_t)b * cKA + cPRE + j, 0.f);
    } else if (idx < 81920) {                   // XD dec_h zero
      const size_t r = idx - 49152;
      const int b = (int)(r >> 10), h = (int)(r & 1023);
      st_sc(ws + WS_XD + (size_t)b * cKD + (cAR + cENCD) + h, 0.f);
    }
  }
  ++ph; gbar(ctrs, ph);

  for (int t = 0; t <= cNSTEP; ++t) {
    const int p = t & 1;
    const float* xabuf = ws + WS_XA + (size_t)(t & 1) * cB * cKA;
    float* xa2 = ws + WS_XA + (size_t)((t + 1) & 1) * cB * cKA;
    // ---- Phase A ----
    if (slot < cNSA) {
      if (t < cNSTEP)
        gemv2<128, cRDA, cNSA>(wlds, nullptr, xabuf + k0A, cKA,
                               ws + WS_GA + ((size_t)p * 8 + xcd) * (cNSA * cB * 512),
                               slot, xsA);
    } else if (slot < cNSA + cNSD) {
      if (t >= 1)
        gemv2<160, cRDD, cNSD>(wlds, wstrD, ws + WS_XD + k0D, cKD,
                               ws + WS_GD + ((size_t)p * 8 + xcd) * (cNSD * cB * 512),
                               sD, xsD);
    }
    ++ph; gbar(ctrs, ph);
    // ---- Phase B ----
    if (slot == 0) {
      if (t < cNSTEP) attn_cell(a, ws, xcd, t, p, xa2, hs);
    } else if (slot == 1) {
      if (t >= 1) dec_cell2(a, ws, xcd, t - 1, p);
    } else if (slot == 2) {
      if (t + 1 < cNSTEP) {
        for (int i = tid; i < 1024; i += 512) {
          const int b = xcd * 4 + (i >> 8), j = i & 255;
          st_sc(xa2 + (size_t)b * cKA + j,
                ws[WS_XPRE + ((size_t)(t + 1) * cB + b) * cPRE + j]);
        }
      }
    } else if (slot == 30) {
      if (t < cNSTEP) {
        attention(a, ws, xcd * 4 + 0, t, xa2, *at);
        attention(a, ws, xcd * 4 + 1, t, xa2, *at);
      }
    } else if (slot == 31) {
      if (t < cNSTEP) {
        attention(a, ws, xcd * 4 + 2, t, xa2, *at);
        attention(a, ws, xcd * 4 + 3, t, xa2, *at);
      }
    }
    ++ph; gbar(ctrs, ph);
  }
  mel_proj(a, ws, melred);
}

// ---------------- host ----------------
extern "C" void kernel_launch(void* const* d_in, const int* in_sizes, int n_in,
                              void* d_out, int out_size, void* d_ws, size_t ws_size,
                              hipStream_t stream) {
  (void)in_sizes; (void)n_in; (void)out_size;
  Args a;
  a.enc = (const float*)d_in[0];
  a.inputs = (const float*)d_in[1];
  a.mlen = (const int*)d_in[2];
  a.W1 = (const float*)d_in[3];  a.b1 = (const float*)d_in[4];
  a.W2 = (const float*)d_in[5];  a.b2 = (const float*)d_in[6];
  a.Wm = (const float*)d_in[7];
  a.Wih_a = (const float*)d_in[8];  a.Whh_a = (const float*)d_in[9];
  a.bih_a = (const float*)d_in[10]; a.bhh_a = (const float*)d_in[11];
  a.Wq = (const float*)d_in[12];
  a.conv_w = (const float*)d_in[13]; a.conv_b = (const float*)d_in[14];
  a.WL = (const float*)d_in[15];     a.v = (const float*)d_in[16];
  a.Wih_d = (const float*)d_in[17];  a.Whh_d = (const float*)d_in[18];
  a.bih_d = (const float*)d_in[19];  a.bhh_d = (const float*)d_in[20];
  a.Wmel = (const float*)d_in[21];   a.bmel = (const float*)d_in[22];
  a.Wstop = (const float*)d_in[23];  a.bstop = (const float*)d_in[24];
  a.out = (float*)d_out;
  a.ws = (float*)d_ws;

  if (ws_size < WS_TOTAL * sizeof(float)) {
    fprintf(stderr, "kernel_launch: ws too small: need %zu bytes, have %zu\n",
            WS_TOTAL * sizeof(float), ws_size);
    return;
  }

  float* ws = a.ws;
  ushortT* watb = (ushortT*)(ws + WS_WATB);
  ushortT* wdtb = (ushortT*)(ws + WS_WDTB);
  k_transpose_b16<<<dim3((768 / 64) * (4096 / 64)), dim3(256), 0, stream>>>(
      a.Wih_a, watb, 4096, 768, cNG);
  k_transpose_b16<<<dim3((1024 / 64) * (4096 / 64)), dim3(256), 0, stream>>>(
      a.Whh_a, watb + (size_t)768 * cNG, 4096, 1024, cNG);
  k_transpose_b16<<<dim3((1536 / 64) * (4096 / 64)), dim3(256), 0, stream>>>(
      a.Wih_d, wdtb, 4096, 1536, cNG);
  k_transpose_b16<<<dim3((1024 / 64) * (4096 / 64)), dim3(256), 0, stream>>>(
      a.Whh_d, wdtb + (size_t)1536 * cNG, 4096, 1024, cNG);
  k_transpose<<<dim3((1024 / 64) * (128 / 64)), dim3(256), 0, stream>>>(
      a.Wq, ws + WS_WQT, 128, 1024, cAD);
  k_transpose<<<dim3((512 / 64) * (128 / 64)), dim3(256), 0, stream>>>(
      a.Wm, ws + WS_WMTR, 128, 512, cAD);

  k_prep_small<<<dim3((cKM * cNMP + 255) / 256), dim3(256), 0, stream>>>(a);
  k_prenet1<<<dim3(8000), dim3(256), 0, stream>>>(a);
  k_prenet2<<<dim3(8000), dim3(256), 0, stream>>>(a);
  k_pm<<<dim3(4096), dim3(256), 0, stream>>>(a);

  hipError_t e0 = hipFuncSetAttribute((const void*)k_loop,
                                      hipFuncAttributeMaxDynamicSharedMemorySize, cDYN);
  if (e0 != hipSuccess)
    fprintf(stderr, "kernel_launch: setattr failed: %s\n", hipGetErrorString(e0));

  void* params[] = { (void*)&a };
  hipError_t err = hipLaunchCooperativeKernel((const void*)k_loop, dim3(256), dim3(512),
                                              params, cDYN, stream);
  if (err != hipSuccess) {
    fprintf(stderr, "kernel_launch: cooperative launch failed: %s\n",
            hipGetErrorString(err));
  }
}

// Round 7
// 78818.823 us; speedup vs baseline: 1.6512x; 1.6512x over previous
//
#include <hip/hip_runtime.h>
#include <cstdio>

// ---------------- dims ----------------
static constexpr int cB = 32, cTENC = 256, cENCD = 512, cTDEC = 500, cMEL = 80,
    cNSTEP = 250, cPRE = 256, cAD = 128, cAR = 1024, cDR = 1024, cFLT = 32,
    cKSZ = 31, cPADC = 15, cNG = 4096;
static constexpr int cKA = cPRE + cENCD + cAR;   // 1792 : [x | ctx | h_a]
static constexpr int cKD = cAR + cENCD + cDR;    // 2560 : [h_a | ctx | dec_h]
static constexpr int cKM = cDR + cENCD;          // 1536 : [dec_h | ctx]
static constexpr int cNMP = 192;                 // padded 161 (160 mel + 1 stop)
static constexpr int cNSA = 14;                  // attn k-splits (span 128)
static constexpr int cNSD = 16;                  // dec  k-splits (span 160)
static constexpr int cDYN = 98304;               // dyn LDS: forces 1 WG/CU (2x98K > 160K)

typedef unsigned short ushortT;
typedef unsigned int uintT;
typedef unsigned long long ullT;

// ---------------- output layout (floats) ----------------
static constexpr size_t MEL_OFF = 0;
static constexpr size_t STOP_OFF = (size_t)cB * cTDEC * cMEL;      // 1,280,000
static constexpr size_t ATT_OFF = STOP_OFF + (size_t)cB * cTDEC;   // 1,296,000

// ---------------- workspace layout (float units) ----------------
// WATB: bf16 [8 xcd][cKA][512]  (col = gate*1024 + xcd*128 + c packed as g*128+c)
// WDTB: bf16 [8 xcd][cKD][512]
static constexpr size_t WS_WATB = 0;                                   // us[8][1792][512]
static constexpr size_t WS_WDTB = WS_WATB + (size_t)cKA * cNG / 2;     // us[8][2560][512]
static constexpr size_t WS_WMT  = WS_WDTB + (size_t)cKD * cNG / 2;     // f[1536][192]
static constexpr size_t WS_WQT  = WS_WMT  + (size_t)cKM * cNMP;        // f[1024][128]
static constexpr size_t WS_WMTR = WS_WQT  + (size_t)cAR * cAD;         // f[512][128]
static constexpr size_t WS_PM   = WS_WMTR + (size_t)cENCD * cAD;       // f[32][256][128]
static constexpr size_t WS_XPRE = WS_PM   + (size_t)cB * cTENC * cAD;  // f[250][32][256]
static constexpr size_t WS_XA   = WS_XPRE + (size_t)cNSTEP * cPRE * cB;// f[2][32][1792]
static constexpr size_t WS_XD   = WS_XA   + (size_t)2 * cB * cKA;      // f[32][2560]
static constexpr size_t WS_CA   = WS_XD   + (size_t)cB * cKD;          // f[8][32][128] private
static constexpr size_t WS_CD   = WS_CA   + (size_t)8 * cB * 128;      // f[8][32][128] private
static constexpr size_t WS_CUMP = WS_CD   + (size_t)8 * cB * 128;      // f[32][256] private
static constexpr size_t WS_PQP  = WS_CUMP + (size_t)cB * cTENC;        // f[8][32][128] (sc)
static constexpr size_t WS_CTR  = WS_PQP  + (size_t)8 * cB * 128;      // u32[128]
static constexpr size_t WS_FLG  = WS_CTR  + 128;                       // u32[64]
static constexpr size_t WS_SLOT = WS_FLG  + 64;                        // u32[64]
static constexpr size_t WS_GA   = WS_SLOT + 64;                        // f[2][8][14][32][512]
static constexpr size_t WS_GD   = WS_GA   + (size_t)2 * 8 * cNSA * cB * 512;
static constexpr size_t WS_PROJ = WS_GD   + (size_t)2 * 8 * cNSD * cB * 512; // f[250][32][1536]
static constexpr size_t WS_TOTAL = WS_PROJ + (size_t)cNSTEP * cB * cKM;
// X1 (prenet intermediate) aliases GA region: used only pre-loop.
static constexpr size_t WS_X1   = WS_GA;                               // f[250][32][256]

struct Args {
  const float *enc, *inputs;
  const int *mlen;
  const float *W1, *b1, *W2, *b2, *Wm;
  const float *Wih_a, *Whh_a, *bih_a, *bhh_a;
  const float *Wq, *conv_w, *conv_b, *WL, *v;
  const float *Wih_d, *Whh_d, *bih_d, *bhh_d;
  const float *Wmel, *bmel, *Wstop, *bstop;
  float *out;
  float *ws;
};

struct AttnSh {
  float pq[cAD];
  float cumext[cTENC + 2 * cPADC];
  float eparts[2][cTENC];
  float e[cTENC];
  float sred[16];
  float loc[cFLT * 257];
  float wl[cAD * 33];
  float cw[cFLT * cKSZ];
  float vv[cAD];
};

// ---------- agent-scope (cross-XCD, via L3) access ----------
__device__ __forceinline__ float ld_sc(const float* p) {
  return __hip_atomic_load(p, __ATOMIC_RELAXED, __HIP_MEMORY_SCOPE_AGENT);
}
__device__ __forceinline__ void st_sc(float* p, float v) {
  __hip_atomic_store(p, v, __ATOMIC_RELAXED, __HIP_MEMORY_SCOPE_AGENT);
}
__device__ __forceinline__ float2 ld_sc2(const float2* p) {
  ullT u = __hip_atomic_load((const ullT*)p, __ATOMIC_RELAXED, __HIP_MEMORY_SCOPE_AGENT);
  float2 r;
  r.x = __uint_as_float((uintT)u);
  r.y = __uint_as_float((uintT)(u >> 32));
  return r;
}
__device__ __forceinline__ void st_sc2(float2* p, float x, float y) {
  ullT u = (ullT)__float_as_uint(x) | ((ullT)__float_as_uint(y) << 32);
  __hip_atomic_store((ullT*)p, u, __ATOMIC_RELAXED, __HIP_MEMORY_SCOPE_AGENT);
}
__device__ __forceinline__ uintT ld_scu(const uintT* p) {
  return __hip_atomic_load(p, __ATOMIC_RELAXED, __HIP_MEMORY_SCOPE_AGENT);
}
__device__ __forceinline__ void st_scu(uintT* p, uintT v) {
  __hip_atomic_store(p, v, __ATOMIC_RELAXED, __HIP_MEMORY_SCOPE_AGENT);
}

// Distributed monotonic grid barrier: 8 counters, 64B apart.
__device__ __forceinline__ void gbar(uintT* ctrs, uintT ph) {
  __syncthreads();
  if (threadIdx.x == 0)
    __hip_atomic_fetch_add(ctrs + (blockIdx.x & 7) * 16, 1u,
                           __ATOMIC_RELAXED, __HIP_MEMORY_SCOPE_AGENT);
  if (threadIdx.x < 8) {
    const uintT target = ph * 32u;
    while (ld_scu(ctrs + threadIdx.x * 16) < target)
      __builtin_amdgcn_s_sleep(2);
  }
  __syncthreads();
}

__device__ __forceinline__ float sigm_f(float x) { return 1.f / (1.f + __expf(-x)); }
__device__ __forceinline__ float tanh_f(float x) {
  float e = __expf(2.f * x);
  return 1.f - 2.f / (e + 1.f);
}

__device__ __forceinline__ void fma8x4(float (&acc)[8][4], const uint4 w, const float4 x4) {
  float wf[8];
  wf[0] = __uint_as_float(w.x << 16);
  wf[1] = __uint_as_float(w.x & 0xFFFF0000u);
  wf[2] = __uint_as_float(w.y << 16);
  wf[3] = __uint_as_float(w.y & 0xFFFF0000u);
  wf[4] = __uint_as_float(w.z << 16);
  wf[5] = __uint_as_float(w.z & 0xFFFF0000u);
  wf[6] = __uint_as_float(w.w << 16);
  wf[7] = __uint_as_float(w.w & 0xFFFF0000u);
  const float xv[4] = {x4.x, x4.y, x4.z, x4.w};
#pragma unroll
  for (int c = 0; c < 8; ++c)
#pragma unroll
    for (int j = 0; j < 4; ++j) acc[c][j] = fmaf(wf[c], xv[j], acc[c][j]);
}

// Batch-32 GEMV partial: weights from GLOBAL (plain, L2/L3-cached, [k][512] rows),
// x staged to LDS via sc, partials stored PLAIN (XCD-local consumer).
// PF=8 register prefetch pipeline (round-4 structure, no LDS weight reads).
template <int KSPAN, int NS>
static __device__ void gemv3(const ushortT* __restrict__ wb,
                             const float* __restrict__ xb, int xstride,
                             float* __restrict__ partbase, int slot,
                             float* __restrict__ xs) {
  const int tid = threadIdx.x;
  {
    const int b = tid >> 4, kt = tid & 15;
    const float* src = xb + (size_t)b * xstride;
    for (int kp = kt; kp < KSPAN / 2; kp += 16) {
      float2 u = ld_sc2((const float2*)(src + 2 * kp));
      xs[(2 * kp) * 36 + b] = u.x;
      xs[(2 * kp + 1) * 36 + b] = u.y;
    }
  }
  __syncthreads();
  const int cq = tid & 63, bq = tid >> 6;
  const ushortT* wp = wb + cq * 8;
  const float* xp = xs + bq * 4;
  float acc[8][4];
#pragma unroll
  for (int c = 0; c < 8; ++c)
#pragma unroll
    for (int j = 0; j < 4; ++j) acc[c][j] = 0.f;

  constexpr int PF = 8;
  uint4 wbuf[PF];
  float4 xbuf[PF];
#pragma unroll
  for (int i = 0; i < PF; ++i) {
    wbuf[i] = *(const uint4*)(wp + (size_t)i * 512);
    xbuf[i] = *(const float4*)(xp + i * 36);
  }
  for (int kb = 0; kb < KSPAN; kb += PF) {
#pragma unroll
    for (int i = 0; i < PF; ++i) {
      const uint4 w = wbuf[i];
      const float4 x4 = xbuf[i];
      const int kn = kb + i + PF;
      wbuf[i] = *(const uint4*)(wp + (size_t)kn * 512);   // over-read benign (in ws)
      xbuf[i] = *(const float4*)(xp + kn * 36);           // LDS pad covers
      fma8x4(acc, w, x4);
    }
  }
  const int b0 = bq * 4;
#pragma unroll
  for (int j = 0; j < 4; ++j) {
    float* dst = partbase + (((size_t)slot * cB + (b0 + j)) * 512 + cq * 8);
    float4 o0, o1;
    o0.x = acc[0][j]; o0.y = acc[1][j]; o0.z = acc[2][j]; o0.w = acc[3][j];
    o1.x = acc[4][j]; o1.y = acc[5][j]; o1.z = acc[6][j]; o1.w = acc[7][j];
    *(float4*)dst = o0;
    *(float4*)(dst + 4) = o1;
  }
  __syncthreads();
}

// attn-LSTM cell for this XCD's 128-h block (slot 0). Publishes h (sc), pq_part (sc), flag.
static __device__ void attn_cell(const Args& a, float* ws, int xcd, int t, int p,
                                 float* __restrict__ xa2, float* __restrict__ hs) {
  const int tid = threadIdx.x;
  const int b = tid >> 4, h0 = (tid & 15) * 8;
  const float* base = ws + WS_GA + ((size_t)p * 8 + xcd) * (cNSA * cB * 512);
  float g4[4][8];
#pragma unroll
  for (int g = 0; g < 4; ++g) {
    const int n = g * 1024 + xcd * 128 + h0;
#pragma unroll
    for (int e = 0; e < 8; ++e) g4[g][e] = a.bih_a[n + e] + a.bhh_a[n + e];
  }
  for (int s = 0; s < cNSA; ++s) {
    const float* pb = base + ((size_t)s * cB + b) * 512;
#pragma unroll
    for (int g = 0; g < 4; ++g) {
      const float4 a0 = *(const float4*)(pb + g * 128 + h0);
      const float4 a1 = *(const float4*)(pb + g * 128 + h0 + 4);
      g4[g][0] += a0.x; g4[g][1] += a0.y; g4[g][2] += a0.z; g4[g][3] += a0.w;
      g4[g][4] += a1.x; g4[g][5] += a1.y; g4[g][6] += a1.z; g4[g][7] += a1.w;
    }
  }
  float* cp = ws + WS_CA + ((size_t)xcd * cB + b) * 128 + h0;   // private, plain
  float hn[8];
#pragma unroll
  for (int e = 0; e < 8; ++e) {
    const float cn = sigm_f(g4[1][e]) * cp[e] + sigm_f(g4[0][e]) * tanh_f(g4[2][e]);
    hn[e] = sigm_f(g4[3][e]) * tanh_f(cn);
    cp[e] = cn;
  }
  float* xd = ws + WS_XD + (size_t)b * cKD + xcd * 128 + h0;
  float* xa = xa2 + (size_t)b * cKA + (cPRE + cENCD) + xcd * 128 + h0;
#pragma unroll
  for (int e = 0; e < 8; e += 2) {
    st_sc2((float2*)(xd + e), hn[e], hn[e + 1]);
    st_sc2((float2*)(xa + e), hn[e], hn[e + 1]);
  }
#pragma unroll
  for (int e = 0; e < 8; ++e) hs[b * 132 + h0 + e] = hn[e];
  __syncthreads();
  // pq partial: pqp[xcd][b][d] = sum_h hn[b][h] * WqT[xcd*128+h][d]
  {
    const int d = tid & 127, bg = tid >> 7;
    const float* wqt = ws + WS_WQT + (size_t)(xcd * 128) * cAD + d;
    for (int bb = bg * 8; bb < bg * 8 + 8; ++bb) {
      float acc = 0.f;
      for (int h = 0; h < 128; ++h) acc = fmaf(hs[bb * 132 + h], wqt[(size_t)h * cAD], acc);
      st_sc(ws + WS_PQP + ((size_t)xcd * cB + bb) * cAD + d, acc);
    }
  }
  __syncthreads();
  if (tid == 0) st_scu((uintT*)(ws + WS_FLG) + xcd * 8, (uintT)(t + 1));
}

// dec-LSTM cell for this XCD's 128-h block (slot 1), step s.
static __device__ void dec_cell2(const Args& a, float* ws, int xcd, int s, int p) {
  const int tid = threadIdx.x;
  const int b = tid >> 4, h0 = (tid & 15) * 8;
  const float* base = ws + WS_GD + ((size_t)p * 8 + xcd) * (cNSD * cB * 512);
  float g4[4][8];
#pragma unroll
  for (int g = 0; g < 4; ++g) {
    const int n = g * 1024 + xcd * 128 + h0;
#pragma unroll
    for (int e = 0; e < 8; ++e) g4[g][e] = a.bih_d[n + e] + a.bhh_d[n + e];
  }
  for (int sl = 0; sl < cNSD; ++sl) {
    const float* pb = base + ((size_t)sl * cB + b) * 512;
#pragma unroll
    for (int g = 0; g < 4; ++g) {
      const float4 a0 = *(const float4*)(pb + g * 128 + h0);
      const float4 a1 = *(const float4*)(pb + g * 128 + h0 + 4);
      g4[g][0] += a0.x; g4[g][1] += a0.y; g4[g][2] += a0.z; g4[g][3] += a0.w;
      g4[g][4] += a1.x; g4[g][5] += a1.y; g4[g][6] += a1.z; g4[g][7] += a1.w;
    }
  }
  float* cp = ws + WS_CD + ((size_t)xcd * cB + b) * 128 + h0;
  float hn[8];
#pragma unroll
  for (int e = 0; e < 8; ++e) {
    const float cn = sigm_f(g4[1][e]) * cp[e] + sigm_f(g4[0][e]) * tanh_f(g4[2][e]);
    hn[e] = sigm_f(g4[3][e]) * tanh_f(cn);
    cp[e] = cn;
  }
  float* xd = ws + WS_XD + (size_t)b * cKD + (cAR + cENCD) + xcd * 128 + h0;
  float* pj = ws + WS_PROJ + ((size_t)s * cB + b) * cKM + xcd * 128 + h0;
#pragma unroll
  for (int e = 0; e < 8; e += 2) {
    st_sc2((float2*)(xd + e), hn[e], hn[e + 1]);
    st_sc2((float2*)(pj + e), hn[e], hn[e + 1]);
  }
}

// Attention for batch b at step t (slots 28-31, one batch each).
static __device__ void attention(const Args& a, float* ws, int b, int t,
                                 float* __restrict__ xa2, AttnSh& sh) {
  const int tid = threadIdx.x;
  if (tid < 8) {
    const uintT* flg = (const uintT*)(ws + WS_FLG) + tid * 8;
    while (ld_scu(flg) < (uintT)(t + 1)) __builtin_amdgcn_s_sleep(1);
  }
  __syncthreads();
  if (tid < cAD) {
    float s = 0.f;
#pragma unroll
    for (int x = 0; x < 8; ++x) s += ld_sc(ws + WS_PQP + ((size_t)x * cB + b) * cAD + tid);
    sh.pq[tid] = s;
  }
  if (tid < cTENC) sh.cumext[cPADC + tid] = ws[WS_CUMP + (size_t)b * cTENC + tid];
  if (tid >= cTENC && tid < cTENC + 30) {
    const int q = tid - cTENC;
    sh.cumext[q < cPADC ? q : cTENC + q] = 0.f;
  }
  for (int i = tid; i < cAD * 33; i += 512) {
    const int dd = i / 33, f = i - dd * 33;
    sh.wl[i] = (f < cFLT) ? a.WL[dd * cFLT + f] : 0.f;
  }
  for (int i = tid; i < cFLT * cKSZ; i += 512) sh.cw[i] = a.conv_w[i];
  if (tid < cAD) sh.vv[tid] = a.v[tid];
  __syncthreads();
  for (int i = tid; i < cFLT * cTENC; i += 512) {
    const int f = i >> 8, te = i & 255;
    float s = a.conv_b[f];
#pragma unroll
    for (int j = 0; j < cKSZ; ++j) s = fmaf(sh.cumext[te + j], sh.cw[f * cKSZ + j], s);
    sh.loc[f * 257 + te] = s;
  }
  __syncthreads();
  {
    const int d = tid & 127, tq = tid >> 7, wv = tid >> 6;
    float wlr[cFLT];
#pragma unroll
    for (int f = 0; f < cFLT; ++f) wlr[f] = sh.wl[d * 33 + f];
    const float pqd = sh.pq[d], vd = sh.vv[d];
    const float* pmb = ws + WS_PM + (size_t)b * cTENC * cAD;
    for (int tt = 0; tt < cTENC / 4; ++tt) {
      const int te = tt * 4 + tq;
      float s = pqd + pmb[(size_t)te * cAD + d];
#pragma unroll
      for (int f = 0; f < cFLT; ++f) s = fmaf(sh.loc[f * 257 + te], wlr[f], s);
      float pv = tanh_f(s) * vd;
#pragma unroll
      for (int off = 32; off > 0; off >>= 1) pv += __shfl_xor(pv, off, 64);
      if ((tid & 63) == 0) sh.eparts[wv & 1][te] = pv;
    }
  }
  __syncthreads();
  const int mlen = a.mlen[b];
  if (tid < cTENC) {
    float ev = sh.eparts[0][tid] + sh.eparts[1][tid];
    if (tid >= mlen) ev = -1e9f;
    sh.e[tid] = ev;
  }
  __syncthreads();
  const int wv = tid >> 6;
  {
    float xv = sh.e[tid & 255];
#pragma unroll
    for (int off = 32; off > 0; off >>= 1) xv = fmaxf(xv, __shfl_xor(xv, off, 64));
    if ((tid & 63) == 0) sh.sred[wv] = xv;
  }
  __syncthreads();
  float m = sh.sred[0];
#pragma unroll
  for (int i = 1; i < 8; ++i) m = fmaxf(m, sh.sred[i]);
  const float pex = (tid < cTENC) ? __expf(sh.e[tid] - m) : 0.f;
  {
    float sv = pex;
#pragma unroll
    for (int off = 32; off > 0; off >>= 1) sv += __shfl_xor(sv, off, 64);
    if ((tid & 63) == 0) sh.sred[8 + wv] = sv;
  }
  __syncthreads();
  float ssum = 0.f;
#pragma unroll
  for (int i = 0; i < 8; ++i) ssum += sh.sred[8 + i];
  const float rs = 1.f / ssum;
  if (tid < cTENC) {
    const float al = pex * rs;
    sh.e[tid] = al;
    a.out[ATT_OFF + ((size_t)b * cNSTEP + t) * cTENC + tid] = al;
    ws[WS_CUMP + (size_t)b * cTENC + tid] = sh.cumext[cPADC + tid] + al;  // private
  }
  __syncthreads();
  {
    const int k = tid;   // 512 = ENCD
    float acc = 0.f;
    const float* encb = a.enc + (size_t)b * cTENC * cENCD + k;
    for (int te = 0; te < cTENC; ++te) acc = fmaf(sh.e[te], encb[(size_t)te * cENCD], acc);
    st_sc(xa2 + (size_t)b * cKA + cPRE + k, acc);
    st_sc(ws + WS_XD + (size_t)b * cKD + cAR + k, acc);
    st_sc(ws + WS_PROJ + ((size_t)t * cB + b) * cKM + cDR + k, acc);
  }
  __syncthreads();
}

// Post-loop batched mel/stop projection (plain loads; PROJ [t][b][k]).
static __device__ void mel_proj(const Args& a, float* ws, float* melred) {
  const int tid = threadIdx.x;
  const int c = tid & 255, sub = tid >> 8;
  for (int t = blockIdx.x; t < cNSTEP; t += gridDim.x) {
    float acc[cB];
#pragma unroll
    for (int b = 0; b < cB; ++b) acc[b] = 0.f;
    if (c < 161) {
      const float* wmt = ws + WS_WMT;
      const float* xr0 = ws + WS_PROJ + (size_t)t * cB * cKM;
      const int k0 = sub * 768;
      for (int k = k0; k < k0 + 768; ++k) {
        const float w = wmt[(size_t)k * cNMP + c];
#pragma unroll
        for (int b = 0; b < cB; ++b) acc[b] = fmaf(w, xr0[(size_t)b * cKM + k], acc[b]);
      }
    }
    __syncthreads();
    if (sub == 1 && c < 161) {
#pragma unroll
      for (int b = 0; b < cB; ++b) melred[b * 164 + c] = acc[b];
    }
    __syncthreads();
    if (sub == 0 && c < 161) {
      if (c < 160) {
        const int fr = c / 80, mm = c % 80;
        const float bm = a.bmel[c];
#pragma unroll
        for (int b = 0; b < cB; ++b) {
          const float val = acc[b] + melred[b * 164 + c] + bm;
          a.out[MEL_OFF + ((size_t)b * cTDEC + (2 * t + fr)) * cMEL + mm] = val;
        }
      } else {
        const float bs = a.bstop[0];
#pragma unroll
        for (int b = 0; b < cB; ++b) {
          const float sp = sigm_f(acc[b] + melred[b * 164 + c] + bs);
          a.out[STOP_OFF + (size_t)b * cTDEC + 2 * t] = sp;
          a.out[STOP_OFF + (size_t)b * cTDEC + 2 * t + 1] = sp;
        }
      }
    }
    __syncthreads();
  }
}

// ---------------- setup kernels ----------------
__device__ __forceinline__ ushortT f2b(float f) {
  const uintT u = __float_as_uint(f);
  return (ushortT)((u + 0x7FFFu + ((u >> 16) & 1u)) >> 16);   // RNE
}

__global__ void k_transpose(const float* __restrict__ src, float* __restrict__ dst,
                            int N, int K, int dpitch) {
  __shared__ float tile[64][65];
  const int tkn = K >> 6;
  const int tk = blockIdx.x % tkn, tn = blockIdx.x / tkn;
  const int c = threadIdx.x & 63, r4 = threadIdx.x >> 6;
  const int n0 = tn << 6, k0 = tk << 6;
#pragma unroll
  for (int rr = 0; rr < 16; ++rr) {
    const int r = r4 * 16 + rr;
    tile[r][c] = src[(size_t)(n0 + r) * K + k0 + c];
  }
  __syncthreads();
#pragma unroll
  for (int rr = 0; rr < 16; ++rr) {
    const int r = r4 * 16 + rr;
    dst[(size_t)(k0 + r) * dpitch + n0 + c] = tile[c][r];
  }
}

// fp32 [4096][K] -> bf16 [xcd][KR rows][512], rows at offset kofs.
// col n -> (xcd=(n>>7)&7, g=n>>10, c=n&127), packed col = g*128+c.
__global__ void k_transpose_b16x(const float* __restrict__ src, ushortT* __restrict__ dst,
                                 int K, int KR, int kofs) {
  __shared__ float tile[64][65];
  const int tkn = K >> 6;
  const int tk = blockIdx.x % tkn, tn = blockIdx.x / tkn;
  const int c = threadIdx.x & 63, r4 = threadIdx.x >> 6;
  const int n0 = tn << 6, kk0 = tk << 6;
#pragma unroll
  for (int rr = 0; rr < 16; ++rr) {
    const int r = r4 * 16 + rr;
    tile[r][c] = src[(size_t)(n0 + r) * K + kk0 + c];
  }
  __syncthreads();
  const int xcd = (n0 >> 7) & 7, g = n0 >> 10, cb = n0 & 127;
  ushortT* drow = dst + ((size_t)xcd * KR + (kofs + kk0)) * 512 + g * 128 + cb;
#pragma unroll
  for (int rr = 0; rr < 16; ++rr) {
    const int r = r4 * 16 + rr;
    drow[(size_t)r * 512 + c] = f2b(tile[c][r]);
  }
}

__global__ void k_prep_small(Args a) {
  const size_t i = (size_t)blockIdx.x * blockDim.x + threadIdx.x;
  if (i < 256) ((uintT*)(a.ws + WS_CTR))[i] = 0u;   // CTR(128)+FLG(64)+SLOT(64)
  if (i >= (size_t)cKM * cNMP) return;
  const int k = (int)(i / cNMP), c = (int)(i % cNMP);
  a.ws[WS_WMT + i] = (c < 160) ? a.Wmel[(size_t)c * cKM + k]
                               : (c == 160 ? a.Wstop[k] : 0.f);
}

__global__ void k_prenet1(Args a) {
  const size_t i = (size_t)blockIdx.x * blockDim.x + threadIdx.x;
  if (i >= (size_t)cNSTEP * cB * cPRE) return;
  const int j = i & 255, b = (i >> 8) & 31, n = (int)(i >> 13);
  float acc = a.b1[j];
  if (n > 0) {
    const float* fr = a.inputs + ((size_t)b * cTDEC + (2 * n - 1)) * cMEL;
    for (int k = 0; k < cMEL; ++k) acc = fmaf(fr[k], a.W1[j * cMEL + k], acc);
  }
  a.ws[WS_X1 + i] = fmaxf(acc, 0.f);   // [n][b][j]
}

__global__ void k_prenet2(Args a) {
  const size_t i = (size_t)blockIdx.x * blockDim.x + threadIdx.x;
  if (i >= (size_t)cNSTEP * cPRE * cB) return;
  const int j = i & 255, b = (i >> 8) & 31, n = (int)(i >> 13);
  float acc = a.b2[j];
  const float* x1 = a.ws + WS_X1 + ((size_t)n * cB + b) * cPRE;
  for (int k = 0; k < cPRE; ++k) acc = fmaf(x1[k], a.W2[j * cPRE + k], acc);
  a.ws[WS_XPRE + ((size_t)n * cB + b) * cPRE + j] = fmaxf(acc, 0.f);   // [n][b][j]
}

__global__ void k_pm(Args a) {
  const size_t i = (size_t)blockIdx.x * blockDim.x + threadIdx.x;
  if (i >= (size_t)cB * cTENC * cAD) return;
  const int d = i & 127, tt = (i >> 7) & 255, b = (int)(i >> 15);
  float acc = 0.f;
  const float* er = a.enc + ((size_t)b * cTENC + tt) * cENCD;
  const float* wt = a.ws + WS_WMTR;
  for (int k = 0; k < cENCD; ++k) acc = fmaf(er[k], wt[(size_t)k * cAD + d], acc);
  a.ws[WS_PM + i] = acc;
}

// ---------------- persistent cooperative loop ----------------
// Per XCD (32 WGs, dense slots via XCC_ID + atomicAdd):
//   PhA: slot 0-13 attn GEMV(t); slot 14-29 dec GEMV(t-1). Weights: global plain
//        [xcd][k][512] (L2-resident); partials: PLAIN stores, XCD-local, parity dbuf.
//   PhB: slot 0 attn-cell+pq+flag; slot 1 dec-cell(t-1); slot 2 x-copy(t+1);
//        slots 28-31 attention (1 batch each, flag-gated).
__global__ void __launch_bounds__(512, 1) k_loop(Args a) {
  extern __shared__ char dyn[];
  float* ws = a.ws;
  uintT* ctrs = (uintT*)(ws + WS_CTR);
  const int tid = threadIdx.x;

  __shared__ int s_xcd, s_slot;
  if (tid == 0) {
    const int x = (int)(__builtin_amdgcn_s_getreg((31 << 11) | 20) & 7);  // HW_REG_XCC_ID
    const uintT sl = __hip_atomic_fetch_add((uintT*)(ws + WS_SLOT) + x * 8, 1u,
                                            __ATOMIC_RELAXED, __HIP_MEMORY_SCOPE_AGENT);
    s_xcd = x;
    s_slot = (int)sl;
  }
  __syncthreads();
  const int xcd = s_xcd, slot = s_slot;
  uintT ph = 0;

  const ushortT* watb = (const ushortT*)(ws + WS_WATB);
  const ushortT* wdtb = (const ushortT*)(ws + WS_WDTB);
  float* xs = (float*)dyn;                 // phase A (168*36 floats)
  float* hs = (float*)dyn;                 // slot0 phase B
  AttnSh* at = (AttnSh*)dyn;               // slots 28-31 phase B
  float* melred = (float*)dyn;             // post-loop

  const int k0A = slot * 128;
  const int sD = slot - 14, k0D = sD * 160;
  const ushortT* wbA = watb + ((size_t)xcd * cKA + k0A) * 512;
  const ushortT* wbD = wdtb + ((size_t)xcd * cKD + (sD >= 0 ? k0D : 0)) * 512;

  // ---- one-time init ----
  if (slot == 0) {
    float* c = ws + WS_CA + (size_t)xcd * cB * 128;
    for (int i = tid; i < cB * 128; i += 512) c[i] = 0.f;
  } else if (slot == 1) {
    float* c = ws + WS_CD + (size_t)xcd * cB * 128;
    for (int i = tid; i < cB * 128; i += 512) c[i] = 0.f;
  } else if (slot == 2) {
    for (int i = tid; i < 1024; i += 512) {   // x0 for this XCD's 4 batches
      const int b = xcd * 4 + (i >> 8), j = i & 255;
      st_sc(ws + WS_XA + (size_t)b * cKA + j, ws[WS_XPRE + (size_t)b * cPRE + j]);
    }
  } else if (slot >= 28 && slot < 32) {
    const int b = xcd * 4 + (slot - 28);
    if (tid < cTENC) ws[WS_CUMP + (size_t)b * cTENC + tid] = 0.f;
  }
  {
    const int g = xcd * 32 + (slot < 32 ? slot : 31);
    const size_t idx = (size_t)g * 512 + tid;
    if (idx < 49152) {                          // XA[0] ctx+h zero
      const int b = (int)(idx / 1536), j = (int)(idx % 1536);
      st_sc(ws + WS_XA + (size_t)b * cKA + cPRE + j, 0.f);
    } else if (idx < 81920) {                   // XD dec_h zero
      const size_t r = idx - 49152;
      const int b = (int)(r >> 10), h = (int)(r & 1023);
      st_sc(ws + WS_XD + (size_t)b * cKD + (cAR + cENCD) + h, 0.f);
    }
  }
  ++ph; gbar(ctrs, ph);

  for (int t = 0; t <= cNSTEP; ++t) {
    const int p = t & 1;
    const float* xabuf = ws + WS_XA + (size_t)(t & 1) * cB * cKA;
    float* xa2 = ws + WS_XA + (size_t)((t + 1) & 1) * cB * cKA;
    // ---- Phase A ----
    if (slot < cNSA) {
      if (t < cNSTEP)
        gemv3<128, cNSA>(wbA, xabuf + k0A, cKA,
                         ws + WS_GA + ((size_t)p * 8 + xcd) * (cNSA * cB * 512),
                         slot, xs);
    } else if (slot < cNSA + cNSD) {
      if (t >= 1)
        gemv3<160, cNSD>(wbD, ws + WS_XD + k0D, cKD,
                         ws + WS_GD + ((size_t)p * 8 + xcd) * (cNSD * cB * 512),
                         sD, xs);
    }
    ++ph; gbar(ctrs, ph);
    // ---- Phase B ----
    if (slot == 0) {
      if (t < cNSTEP) attn_cell(a, ws, xcd, t, p, xa2, hs);
    } else if (slot == 1) {
      if (t >= 1) dec_cell2(a, ws, xcd, t - 1, p);
    } else if (slot == 2) {
      if (t + 1 < cNSTEP) {
        for (int i = tid; i < 1024; i += 512) {
          const int b = xcd * 4 + (i >> 8), j = i & 255;
          st_sc(xa2 + (size_t)b * cKA + j,
                ws[WS_XPRE + ((size_t)(t + 1) * cB + b) * cPRE + j]);
        }
      }
    } else if (slot >= 28 && slot < 32) {
      if (t < cNSTEP) attention(a, ws, xcd * 4 + (slot - 28), t, xa2, *at);
    }
    ++ph; gbar(ctrs, ph);
  }
  mel_proj(a, ws, melred);
}

// ---------------- host ----------------
extern "C" void kernel_launch(void* const* d_in, const int* in_sizes, int n_in,
                              void* d_out, int out_size, void* d_ws, size_t ws_size,
                              hipStream_t stream) {
  (void)in_sizes; (void)n_in; (void)out_size;
  Args a;
  a.enc = (const float*)d_in[0];
  a.inputs = (const float*)d_in[1];
  a.mlen = (const int*)d_in[2];
  a.W1 = (const float*)d_in[3];  a.b1 = (const float*)d_in[4];
  a.W2 = (const float*)d_in[5];  a.b2 = (const float*)d_in[6];
  a.Wm = (const float*)d_in[7];
  a.Wih_a = (const float*)d_in[8];  a.Whh_a = (const float*)d_in[9];
  a.bih_a = (const float*)d_in[10]; a.bhh_a = (const float*)d_in[11];
  a.Wq = (const float*)d_in[12];
  a.conv_w = (const float*)d_in[13]; a.conv_b = (const float*)d_in[14];
  a.WL = (const float*)d_in[15];     a.v = (const float*)d_in[16];
  a.Wih_d = (const float*)d_in[17];  a.Whh_d = (const float*)d_in[18];
  a.bih_d = (const float*)d_in[19];  a.bhh_d = (const float*)d_in[20];
  a.Wmel = (const float*)d_in[21];   a.bmel = (const float*)d_in[22];
  a.Wstop = (const float*)d_in[23];  a.bstop = (const float*)d_in[24];
  a.out = (float*)d_out;
  a.ws = (float*)d_ws;

  if (ws_size < WS_TOTAL * sizeof(float)) {
    fprintf(stderr, "kernel_launch: ws too small: need %zu bytes, have %zu\n",
            WS_TOTAL * sizeof(float), ws_size);
    return;
  }

  float* ws = a.ws;
  ushortT* watb = (ushortT*)(ws + WS_WATB);
  ushortT* wdtb = (ushortT*)(ws + WS_WDTB);
  // Big weights -> bf16, per-XCD [xcd][k][512] gate-strip layout.
  k_transpose_b16x<<<dim3((768 / 64) * (4096 / 64)), dim3(256), 0, stream>>>(
      a.Wih_a, watb, 768, cKA, 0);
  k_transpose_b16x<<<dim3((1024 / 64) * (4096 / 64)), dim3(256), 0, stream>>>(
      a.Whh_a, watb, 1024, cKA, 768);
  k_transpose_b16x<<<dim3((1536 / 64) * (4096 / 64)), dim3(256), 0, stream>>>(
      a.Wih_d, wdtb, 1536, cKD, 0);
  k_transpose_b16x<<<dim3((1024 / 64) * (4096 / 64)), dim3(256), 0, stream>>>(
      a.Whh_d, wdtb, 1024, cKD, 1536);
  k_transpose<<<dim3((1024 / 64) * (128 / 64)), dim3(256), 0, stream>>>(
      a.Wq, ws + WS_WQT, 128, 1024, cAD);
  k_transpose<<<dim3((512 / 64) * (128 / 64)), dim3(256), 0, stream>>>(
      a.Wm, ws + WS_WMTR, 128, 512, cAD);

  k_prep_small<<<dim3((cKM * cNMP + 255) / 256), dim3(256), 0, stream>>>(a);
  k_prenet1<<<dim3(8000), dim3(256), 0, stream>>>(a);
  k_prenet2<<<dim3(8000), dim3(256), 0, stream>>>(a);
  k_pm<<<dim3(4096), dim3(256), 0, stream>>>(a);

  hipError_t e0 = hipFuncSetAttribute((const void*)k_loop,
                                      hipFuncAttributeMaxDynamicSharedMemorySize, cDYN);
  if (e0 != hipSuccess)
    fprintf(stderr, "kernel_launch: setattr failed: %s\n", hipGetErrorString(e0));

  void* params[] = { (void*)&a };
  hipError_t err = hipLaunchCooperativeKernel((const void*)k_loop, dim3(256), dim3(512),
                                              params, cDYN, stream);
  if (err != hipSuccess) {
    fprintf(stderr, "kernel_launch: cooperative launch failed: %s\n",
            hipGetErrorString(err));
  }
}

// Round 9
// 63890.125 us; speedup vs baseline: 2.0371x; 1.2337x over previous
//
#include <hip/hip_runtime.h>
#include <cstdio>

// ---------------- dims ----------------
static constexpr int cB = 32, cTENC = 256, cENCD = 512, cTDEC = 500, cMEL = 80,
    cNSTEP = 250, cPRE = 256, cAD = 128, cAR = 1024, cDR = 1024, cFLT = 32,
    cKSZ = 31, cPADC = 15, cNG = 4096;
static constexpr int cKA = cPRE + cENCD + cAR;   // 1792 : [x | ctx | h_a]
static constexpr int cKD = cAR + cENCD + cDR;    // 2560 : [h_a | ctx | dec_h]
static constexpr int cKM = cDR + cENCD;          // 1536 : [dec_h | ctx]
static constexpr int cNMP = 192;                 // padded 161 (160 mel + 1 stop)
static constexpr int cNSA = 14;                  // attn k-splits (span 128)
static constexpr int cNSD = 16;                  // dec  k-splits (span 160)

typedef unsigned short ushortT;
typedef unsigned int uintT;
typedef unsigned long long ullT;
typedef float floatx2 __attribute__((ext_vector_type(2)));
typedef float floatx4 __attribute__((ext_vector_type(4)));

// ---------------- output layout (floats) ----------------
static constexpr size_t MEL_OFF = 0;
static constexpr size_t STOP_OFF = (size_t)cB * cTDEC * cMEL;      // 1,280,000
static constexpr size_t ATT_OFF = STOP_OFF + (size_t)cB * cTDEC;   // 1,296,000

// ---------------- workspace layout (float units) ----------------
static constexpr size_t WS_WATB = 0;                                   // us[1792][4096]
static constexpr size_t WS_WDTB = WS_WATB + (size_t)cKA * cNG / 2;     // us[2560][4096]
static constexpr size_t WS_WMT  = WS_WDTB + (size_t)cKD * cNG / 2;     // f[1536][192]
static constexpr size_t WS_WQT  = WS_WMT  + (size_t)cKM * cNMP;        // f[1024][128]
static constexpr size_t WS_WMTR = WS_WQT  + (size_t)cAR * cAD;         // f[512][128]
static constexpr size_t WS_PM   = WS_WMTR + (size_t)cENCD * cAD;       // f[32][256][128]
static constexpr size_t WS_XPRE = WS_PM   + (size_t)cB * cTENC * cAD;  // f[250][32][256] = [n][b][j]
static constexpr size_t WS_XA   = WS_XPRE + (size_t)cNSTEP * cPRE * cB;// f[2][32][1792] = [buf][b][k]
static constexpr size_t WS_XD   = WS_XA   + (size_t)2 * cB * cKA;      // f[32][2560] = [b][k]
static constexpr size_t WS_CA   = WS_XD   + (size_t)cB * cKD;          // f[32][1024] plain
static constexpr size_t WS_CD   = WS_CA   + (size_t)cB * cAR;          // f[32][1024] plain
static constexpr size_t WS_CUM  = WS_CD   + (size_t)cB * cDR;          // f[32][256] plain
static constexpr size_t WS_CTR  = WS_CUM  + (size_t)cB * cTENC;        // u32[128] (8 ctrs x 64B)
static constexpr size_t WS_GA   = WS_CTR  + 128;                       // f[32][14][4096]
static constexpr size_t WS_GD   = WS_GA   + (size_t)cB * cNSA * cNG;   // f[32][16][4096]
static constexpr size_t WS_PROJ = WS_GD   + (size_t)cB * cNSD * cNG;   // f[250][32][1536] = [t][b][k]
static constexpr size_t WS_TOTAL = WS_PROJ + (size_t)cNSTEP * cB * cKM;
// X1 (prenet intermediate) aliases GA region: used only pre-loop.
static constexpr size_t WS_X1   = WS_GA;                               // f[250][32][256]

struct Args {
  const float *enc, *inputs;
  const int *mlen;
  const float *W1, *b1, *W2, *b2, *Wm;
  const float *Wih_a, *Whh_a, *bih_a, *bhh_a;
  const float *Wq, *conv_w, *conv_b, *WL, *v;
  const float *Wih_d, *Whh_d, *bih_d, *bhh_d;
  const float *Wmel, *bmel, *Wstop, *bstop;
  float *out;
  float *ws;
};

union SharedU {
  float xs[(160 + 8) * 36];              // gemv x-slice stage (stride-36 rows, PF pad)
  struct {
    float h[cAR];
    float pq[cAD];
    float cumext[cTENC + 2 * cPADC];
    float eparts[2][cTENC];
    float e[cTENC];
    float sred[16];
    float loc[cFLT * 257];
    float wl[cAD * 33];
    float cw[cFLT * cKSZ];
    float vv[cAD];
  } attn;                                // ~63 KB
  float melred[cB][164];
};

// ---------- agent-scope (cross-XCD coherent) access ----------
__device__ __forceinline__ float ld_sc(const float* p) {
  return __hip_atomic_load(p, __ATOMIC_RELAXED, __HIP_MEMORY_SCOPE_AGENT);
}
__device__ __forceinline__ void st_sc(float* p, float v) {
  __hip_atomic_store(p, v, __ATOMIC_RELAXED, __HIP_MEMORY_SCOPE_AGENT);
}
__device__ __forceinline__ void st_sc2(float* p, float x, float y) {
  ullT u = (ullT)__float_as_uint(x) | ((ullT)__float_as_uint(y) << 32);
  __hip_atomic_store((ullT*)p, u, __ATOMIC_RELAXED, __HIP_MEMORY_SCOPE_AGENT);
}
__device__ __forceinline__ uintT ld_scu(const uintT* p) {
  return __hip_atomic_load(p, __ATOMIC_RELAXED, __HIP_MEMORY_SCOPE_AGENT);
}

// ---- vectorized sc accesses via inline asm (issue-batch + single wait) ----
// ext_vector types lower to VGPR tuples (HIP float4 is a class -> rejected).
// Discipline: issue N loads -> wait_vm0() (s_waitcnt vmcnt(0) + sched_barrier,
// guide rule #18) -> consume.
__device__ __forceinline__ floatx2 ld8_issue(const float* p) {
  floatx2 r;
  asm volatile("global_load_dwordx2 %0, %1, off sc0 sc1" : "=v"(r) : "v"(p));
  return r;
}
__device__ __forceinline__ floatx4 ld16_issue(const float* p) {
  floatx4 r;
  asm volatile("global_load_dwordx4 %0, %1, off sc0 sc1" : "=v"(r) : "v"(p));
  return r;
}
__device__ __forceinline__ void st16(float* p, floatx4 v) {
  asm volatile("global_store_dwordx4 %0, %1, off sc0 sc1" :: "v"(p), "v"(v) : "memory");
}
__device__ __forceinline__ void wait_vm0() {
  asm volatile("s_waitcnt vmcnt(0)" ::: "memory");
  __builtin_amdgcn_sched_barrier(0);
}

// Distributed monotonic grid barrier: 8 counters, 64B apart.
// wait_vm0 first: drain asm stores before arrival.
__device__ __forceinline__ void gbar(uintT* ctrs, uintT ph) {
  wait_vm0();
  __syncthreads();
  if (threadIdx.x == 0)
    __hip_atomic_fetch_add(ctrs + (blockIdx.x & 7) * 16, 1u,
                           __ATOMIC_RELAXED, __HIP_MEMORY_SCOPE_AGENT);
  if (threadIdx.x < 8) {
    const uintT target = ph * 32u;
    while (ld_scu(ctrs + threadIdx.x * 16) < target)
      __builtin_amdgcn_s_sleep(8);
  }
  __syncthreads();
}

__device__ __forceinline__ float sigm_f(float x) { return 1.f / (1.f + __expf(-x)); }
__device__ __forceinline__ float tanh_f(float x) {
  float e = __expf(2.f * x);
  return 1.f - 2.f / (e + 1.f);
}

__device__ __forceinline__ void fma8x4(float (&acc)[8][4], const uint4 w, const float4 x4) {
  float wf[8];
  wf[0] = __uint_as_float(w.x << 16);
  wf[1] = __uint_as_float(w.x & 0xFFFF0000u);
  wf[2] = __uint_as_float(w.y << 16);
  wf[3] = __uint_as_float(w.y & 0xFFFF0000u);
  wf[4] = __uint_as_float(w.z << 16);
  wf[5] = __uint_as_float(w.z & 0xFFFF0000u);
  wf[6] = __uint_as_float(w.w << 16);
  wf[7] = __uint_as_float(w.w & 0xFFFF0000u);
  const float xv[4] = {x4.x, x4.y, x4.z, x4.w};
#pragma unroll
  for (int c = 0; c < 8; ++c)
#pragma unroll
    for (int j = 0; j < 4; ++j) acc[c][j] = fmaf(wf[c], xv[j], acc[c][j]);
}

// Batch-32 GEMV partial. Weights: plain global bf16 [k][4096] (R4-proven PF=8
// pipeline). x: [b][K] via 16B sc loads, transposed into LDS rows stride 36.
// Partials: 16B sc asm stores to part[(b*NS+slot)*4096 + col].
template <int KSPAN, int NS>
static __device__ void gemv4(const ushortT* __restrict__ WT,
                             const float* __restrict__ xbase, int xstride, int k0,
                             float* __restrict__ part, int cb, int slot,
                             float* __restrict__ xs) {
  const int tid = threadIdx.x;
  {
    const int b = tid >> 4, kt = tid & 15;
    const float* src = xbase + (size_t)b * xstride + k0;
    constexpr int NC = (KSPAN / 4 + 15) / 16;   // 2 (128) or 3 (160)
    floatx4 tmp[NC];
#pragma unroll
    for (int c = 0; c < NC; ++c) {
      const int kc = kt + c * 16;
      if (kc < KSPAN / 4) tmp[c] = ld16_issue(src + 4 * kc);
    }
    wait_vm0();
#pragma unroll
    for (int c = 0; c < NC; ++c) {
      const int kc = kt + c * 16;
      if (kc < KSPAN / 4) {
        xs[(4 * kc + 0) * 36 + b] = tmp[c].x;
        xs[(4 * kc + 1) * 36 + b] = tmp[c].y;
        xs[(4 * kc + 2) * 36 + b] = tmp[c].z;
        xs[(4 * kc + 3) * 36 + b] = tmp[c].w;
      }
    }
  }
  __syncthreads();
  const int cq = tid & 63, bq = tid >> 6;
  const int col0 = cb * 512 + cq * 8;
  const ushortT* wp = WT + (size_t)k0 * cNG + col0;
  const float* xp = xs + bq * 4;
  float acc[8][4];
#pragma unroll
  for (int c = 0; c < 8; ++c)
#pragma unroll
    for (int j = 0; j < 4; ++j) acc[c][j] = 0.f;

  constexpr int PF = 8;
  uint4 wbuf[PF];
  float4 xbuf[PF];
#pragma unroll
  for (int i = 0; i < PF; ++i) {
    wbuf[i] = *(const uint4*)(wp + (size_t)i * cNG);
    xbuf[i] = *(const float4*)(xp + i * 36);
  }
  for (int kb = 0; kb < KSPAN; kb += PF) {
#pragma unroll
    for (int i = 0; i < PF; ++i) {
      const uint4 w = wbuf[i];
      const float4 x4 = xbuf[i];
      const int kn = kb + i + PF;
      wbuf[i] = *(const uint4*)(wp + (size_t)kn * cNG);   // over-read benign (in ws)
      xbuf[i] = *(const float4*)(xp + kn * 36);           // LDS pad covers
      fma8x4(acc, w, x4);
    }
  }
  const int b0 = bq * 4;
#pragma unroll
  for (int j = 0; j < 4; ++j) {
    float* dst = &part[(((size_t)(b0 + j)) * NS + slot) * cNG + col0];
    floatx4 o0, o1;
    o0.x = acc[0][j]; o0.y = acc[1][j]; o0.z = acc[2][j]; o0.w = acc[3][j];
    o1.x = acc[4][j]; o1.y = acc[5][j]; o1.z = acc[6][j]; o1.w = acc[7][j];
    st16(dst, o0);
    st16(dst + 4, o1);
  }
}

// Decoder LSTM cell for batch b, step s: each thread owns 2 consecutive h.
static __device__ void dec_cell(const Args& a, float* ws, int b, int s) {
  const int tid = threadIdx.x;
  const float* gd = ws + WS_GD + (size_t)b * cNSD * cNG;
  const int h0 = tid * 2;
  float gg[4][2];
#pragma unroll
  for (int g = 0; g < 4; ++g) {
    const int n = g * cDR + h0;
    floatx2 r[cNSD];
#pragma unroll
    for (int p = 0; p < cNSD; ++p) r[p] = ld8_issue(gd + (size_t)p * cNG + n);
    wait_vm0();
    float s0 = a.bih_d[n] + a.bhh_d[n];
    float s1 = a.bih_d[n + 1] + a.bhh_d[n + 1];
#pragma unroll
    for (int p = 0; p < cNSD; ++p) { s0 += r[p].x; s1 += r[p].y; }
    gg[g][0] = s0; gg[g][1] = s1;
  }
  float* cp = ws + WS_CD + (size_t)b * cDR + h0;   // plain, same-WG state
  float hv[2];
#pragma unroll
  for (int e = 0; e < 2; ++e) {
    const float co = cp[e];
    const float cn = sigm_f(gg[1][e]) * co + sigm_f(gg[0][e]) * tanh_f(gg[2][e]);
    hv[e] = sigm_f(gg[3][e]) * tanh_f(cn);
    cp[e] = cn;
  }
  st_sc2(ws + WS_XD + (size_t)b * cKD + (cAR + cENCD) + h0, hv[0], hv[1]);
  st_sc2(ws + WS_PROJ + ((size_t)s * cB + b) * cKM + h0, hv[0], hv[1]);
}

// Attention workgroup for batch b at step t ([b][k] layouts).
static __device__ void attn_wg(const Args& a, float* ws, int b, int t,
                               float* __restrict__ xa2, SharedU& sh) {
  const int tid = threadIdx.x;
  const float* ga = ws + WS_GA + (size_t)b * cNSA * cNG;
  // 1. reduce ga partials + attn LSTM cell (2 h per thread)
  {
    const int h0 = tid * 2;
    float gg[4][2];
#pragma unroll
    for (int g = 0; g < 4; ++g) {
      const int n = g * cAR + h0;
      floatx2 r[cNSA];
#pragma unroll
      for (int p = 0; p < cNSA; ++p) r[p] = ld8_issue(ga + (size_t)p * cNG + n);
      wait_vm0();
      float s0 = a.bih_a[n] + a.bhh_a[n];
      float s1 = a.bih_a[n + 1] + a.bhh_a[n + 1];
#pragma unroll
      for (int p = 0; p < cNSA; ++p) { s0 += r[p].x; s1 += r[p].y; }
      gg[g][0] = s0; gg[g][1] = s1;
    }
    float* cp = ws + WS_CA + (size_t)b * cAR + h0;   // plain
    float hv[2];
#pragma unroll
    for (int e = 0; e < 2; ++e) {
      const float co = cp[e];
      const float cn = sigm_f(gg[1][e]) * co + sigm_f(gg[0][e]) * tanh_f(gg[2][e]);
      hv[e] = sigm_f(gg[3][e]) * tanh_f(cn);
      cp[e] = cn;
    }
    sh.attn.h[h0] = hv[0];
    sh.attn.h[h0 + 1] = hv[1];
    st_sc2(xa2 + (size_t)b * cKA + (cPRE + cENCD) + h0, hv[0], hv[1]);
    st_sc2(ws + WS_XD + (size_t)b * cKD + h0, hv[0], hv[1]);
  }
  __syncthreads();
  // 2. pq partials (loc as [4][128] scratch) + small LDS loads
  {
    const int d = tid & 127, kc = tid >> 7;
    float acc = 0.f;
    const float* wq = ws + WS_WQT;
    const int k0 = kc * 256;
    for (int k = k0; k < k0 + 256; ++k) acc = fmaf(sh.attn.h[k], wq[(size_t)k * cAD + d], acc);
    sh.attn.loc[kc * 128 + d] = acc;
  }
  for (int i = tid; i < cAD * 33; i += 512) {
    const int dd = i / 33, f = i - dd * 33;
    sh.attn.wl[i] = (f < cFLT) ? a.WL[dd * cFLT + f] : 0.f;
  }
  for (int i = tid; i < cFLT * cKSZ; i += 512) sh.attn.cw[i] = a.conv_w[i];
  if (tid < cAD) sh.attn.vv[tid] = a.v[tid];
  if (tid < cTENC) sh.attn.cumext[cPADC + tid] = ws[WS_CUM + (size_t)b * cTENC + tid];
  if (tid < 2 * cPADC) sh.attn.cumext[tid < cPADC ? tid : cTENC + tid] = 0.f;
  __syncthreads();
  if (tid < cAD)
    sh.attn.pq[tid] = sh.attn.loc[tid] + sh.attn.loc[128 + tid] +
                      sh.attn.loc[256 + tid] + sh.attn.loc[384 + tid];
  __syncthreads();
  // 3. conv31 over cum
  for (int i = tid; i < cFLT * cTENC; i += 512) {
    const int f = i >> 8, te = i & 255;
    float s = a.conv_b[f];
#pragma unroll
    for (int j = 0; j < cKSZ; ++j) s = fmaf(sh.attn.cumext[te + j], sh.attn.cw[f * cKSZ + j], s);
    sh.attn.loc[f * 257 + te] = s;
  }
  __syncthreads();
  // 4. energies
  {
    const int d = tid & 127, tq = tid >> 7, wv = tid >> 6;
    float wlr[cFLT];
#pragma unroll
    for (int f = 0; f < cFLT; ++f) wlr[f] = sh.attn.wl[d * 33 + f];
    const float pqd = sh.attn.pq[d], vd = sh.attn.vv[d];
    const float* pmb = ws + WS_PM + (size_t)b * cTENC * cAD;
    for (int tt = 0; tt < cTENC / 4; ++tt) {
      const int te = tt * 4 + tq;
      float s = pqd + pmb[(size_t)te * cAD + d];
#pragma unroll
      for (int f = 0; f < cFLT; ++f) s = fmaf(sh.attn.loc[f * 257 + te], wlr[f], s);
      float p = tanh_f(s) * vd;
#pragma unroll
      for (int off = 32; off > 0; off >>= 1) p += __shfl_xor(p, off, 64);
      if ((tid & 63) == 0) sh.attn.eparts[wv & 1][te] = p;
    }
  }
  __syncthreads();
  // 5. mask + softmax over 256
  const int mlen = a.mlen[b];
  if (tid < cTENC) {
    float ev = sh.attn.eparts[0][tid] + sh.attn.eparts[1][tid];
    if (tid >= mlen) ev = -1e9f;
    sh.attn.e[tid] = ev;
  }
  __syncthreads();
  const int wv = tid >> 6;
  {
    float xv = sh.attn.e[tid & 255];
#pragma unroll
    for (int off = 32; off > 0; off >>= 1) xv = fmaxf(xv, __shfl_xor(xv, off, 64));
    if ((tid & 63) == 0) sh.attn.sred[wv] = xv;
  }
  __syncthreads();
  float m = sh.attn.sred[0];
#pragma unroll
  for (int i = 1; i < 8; ++i) m = fmaxf(m, sh.attn.sred[i]);
  const float pex = (tid < cTENC) ? __expf(sh.attn.e[tid] - m) : 0.f;
  {
    float sv = pex;
#pragma unroll
    for (int off = 32; off > 0; off >>= 1) sv += __shfl_xor(sv, off, 64);
    if ((tid & 63) == 0) sh.attn.sred[8 + wv] = sv;
  }
  __syncthreads();
  float ssum = 0.f;
#pragma unroll
  for (int i = 0; i < 8; ++i) ssum += sh.attn.sred[8 + i];
  const float rs = 1.f / ssum;
  if (tid < cTENC) {
    const float al = pex * rs;
    sh.attn.e[tid] = al;
    a.out[ATT_OFF + ((size_t)b * cNSTEP + t) * cTENC + tid] = al;
    ws[WS_CUM + (size_t)b * cTENC + tid] = sh.attn.cumext[cPADC + tid] + al;  // plain
  }
  __syncthreads();
  // 6. ctx = align @ encoder_outputs[b]
  {
    const int k = tid;   // 512 = ENCD
    float acc = 0.f;
    const float* encb = a.enc + (size_t)b * cTENC * cENCD + k;
    for (int te = 0; te < cTENC; ++te) acc = fmaf(sh.attn.e[te], encb[(size_t)te * cENCD], acc);
    st_sc(xa2 + (size_t)b * cKA + cPRE + k, acc);
    st_sc(ws + WS_XD + (size_t)b * cKD + cAR + k, acc);
    st_sc(ws + WS_PROJ + ((size_t)t * cB + b) * cKM + cDR + k, acc);
  }
}

// Post-loop batched mel/stop projection (plain loads; PROJ [t][b][k]).
static __device__ void mel_proj(const Args& a, float* ws, SharedU& sh) {
  const int tid = threadIdx.x;
  const int c = tid & 255, sub = tid >> 8;
  for (int t = blockIdx.x; t < cNSTEP; t += gridDim.x) {
    float acc[cB];
#pragma unroll
    for (int b = 0; b < cB; ++b) acc[b] = 0.f;
    if (c < 161) {
      const float* wmt = ws + WS_WMT;
      const float* xr0 = ws + WS_PROJ + (size_t)t * cB * cKM;
      const int k0 = sub * 768;
      for (int k = k0; k < k0 + 768; ++k) {
        const float w = wmt[(size_t)k * cNMP + c];
#pragma unroll
        for (int b = 0; b < cB; ++b) acc[b] = fmaf(w, xr0[(size_t)b * cKM + k], acc[b]);
      }
    }
    __syncthreads();
    if (sub == 1 && c < 161) {
#pragma unroll
      for (int b = 0; b < cB; ++b) sh.melred[b][c] = acc[b];
    }
    __syncthreads();
    if (sub == 0 && c < 161) {
      if (c < 160) {
        const int fr = c / 80, mm = c % 80;
        const float bm = a.bmel[c];
#pragma unroll
        for (int b = 0; b < cB; ++b) {
          const float val = acc[b] + sh.melred[b][c] + bm;
          a.out[MEL_OFF + ((size_t)b * cTDEC + (2 * t + fr)) * cMEL + mm] = val;
        }
      } else {
        const float bs = a.bstop[0];
#pragma unroll
        for (int b = 0; b < cB; ++b) {
          const float sp = sigm_f(acc[b] + sh.melred[b][c] + bs);
          a.out[STOP_OFF + (size_t)b * cTDEC + 2 * t] = sp;
          a.out[STOP_OFF + (size_t)b * cTDEC + 2 * t + 1] = sp;
        }
      }
    }
    __syncthreads();
  }
}

// ---------------- setup kernels ----------------
__device__ __forceinline__ ushortT f2b(float f) {
  const uintT u = __float_as_uint(f);
  return (ushortT)((u + 0x7FFFu + ((u >> 16) & 1u)) >> 16);   // RNE
}

__global__ void k_transpose(const float* __restrict__ src, float* __restrict__ dst,
                            int N, int K, int dpitch) {
  __shared__ float tile[64][65];
  const int tkn = K >> 6;
  const int tk = blockIdx.x % tkn, tn = blockIdx.x / tkn;
  const int c = threadIdx.x & 63, r4 = threadIdx.x >> 6;
  const int n0 = tn << 6, k0 = tk << 6;
#pragma unroll
  for (int rr = 0; rr < 16; ++rr) {
    const int r = r4 * 16 + rr;
    tile[r][c] = src[(size_t)(n0 + r) * K + k0 + c];
  }
  __syncthreads();
#pragma unroll
  for (int rr = 0; rr < 16; ++rr) {
    const int r = r4 * 16 + rr;
    dst[(size_t)(k0 + r) * dpitch + n0 + c] = tile[c][r];
  }
}

__global__ void k_transpose_b16(const float* __restrict__ src, ushortT* __restrict__ dst,
                                int N, int K, int dpitch) {
  __shared__ float tile[64][65];
  const int tkn = K >> 6;
  const int tk = blockIdx.x % tkn, tn = blockIdx.x / tkn;
  const int c = threadIdx.x & 63, r4 = threadIdx.x >> 6;
  const int n0 = tn << 6, k0 = tk << 6;
#pragma unroll
  for (int rr = 0; rr < 16; ++rr) {
    const int r = r4 * 16 + rr;
    tile[r][c] = src[(size_t)(n0 + r) * K + k0 + c];
  }
  __syncthreads();
#pragma unroll
  for (int rr = 0; rr < 16; ++rr) {
    const int r = r4 * 16 + rr;
    dst[(size_t)(k0 + r) * dpitch + n0 + c] = f2b(tile[c][r]);
  }
}

__global__ void k_prep_small(Args a) {
  const size_t i = (size_t)blockIdx.x * blockDim.x + threadIdx.x;
  if (i < 128) ((uintT*)(a.ws + WS_CTR))[i] = 0u;   // barrier counters
  if (i >= (size_t)cKM * cNMP) return;
  const int k = (int)(i / cNMP), c = (int)(i % cNMP);
  a.ws[WS_WMT + i] = (c < 160) ? a.Wmel[(size_t)c * cKM + k]
                               : (c == 160 ? a.Wstop[k] : 0.f);
}

__global__ void k_prenet1(Args a) {
  const size_t i = (size_t)blockIdx.x * blockDim.x + threadIdx.x;
  if (i >= (size_t)cNSTEP * cB * cPRE) return;
  const int j = i & 255, b = (i >> 8) & 31, n = (int)(i >> 13);
  float acc = a.b1[j];
  if (n > 0) {
    const float* fr = a.inputs + ((size_t)b * cTDEC + (2 * n - 1)) * cMEL;
    for (int k = 0; k < cMEL; ++k) acc = fmaf(fr[k], a.W1[j * cMEL + k], acc);
  }
  a.ws[WS_X1 + i] = fmaxf(acc, 0.f);   // [n][b][j]
}

__global__ void k_prenet2(Args a) {
  const size_t i = (size_t)blockIdx.x * blockDim.x + threadIdx.x;
  if (i >= (size_t)cNSTEP * cPRE * cB) return;
  const int j = i & 255, b = (i >> 8) & 31, n = (int)(i >> 13);
  float acc = a.b2[j];
  const float* x1 = a.ws + WS_X1 + ((size_t)n * cB + b) * cPRE;
  for (int k = 0; k < cPRE; ++k) acc = fmaf(x1[k], a.W2[j * cPRE + k], acc);
  a.ws[WS_XPRE + ((size_t)n * cB + b) * cPRE + j] = fmaxf(acc, 0.f);   // [n][b][j]
}

__global__ void k_pm(Args a) {
  const size_t i = (size_t)blockIdx.x * blockDim.x + threadIdx.x;
  if (i >= (size_t)cB * cTENC * cAD) return;
  const int d = i & 127, tt = (i >> 7) & 255, b = (int)(i >> 15);
  float acc = 0.f;
  const float* er = a.enc + ((size_t)b * cTENC + tt) * cENCD;
  const float* wt = a.ws + WS_WMTR;
  for (int k = 0; k < cENCD; ++k) acc = fmaf(er[k], wt[(size_t)k * cAD + d], acc);
  a.ws[WS_PM + i] = acc;
}

__global__ void k_init(Args a) {
  const size_t i = (size_t)blockIdx.x * blockDim.x + threadIdx.x;
  // XA[0] [b][1792]: first 256 from XPRE[0][b][:], rest zero
  if (i < (size_t)cB * cKA) {
    const int b = (int)(i / cKA), k = (int)(i % cKA);
    a.ws[WS_XA + i] = (k < cPRE) ? a.ws[WS_XPRE + (size_t)b * cPRE + k] : 0.f;
  }
  // XD dec_h section zero
  if (i < (size_t)cB * cDR) {
    const int b = (int)(i >> 10), h = (int)(i & 1023);
    a.ws[WS_XD + (size_t)b * cKD + (cAR + cENCD) + h] = 0.f;
  }
  // CA + CD + CUM contiguous zero (32*1024 + 32*1024 + 32*256 = 73728)
  if (i < 73728) a.ws[WS_CA + i] = 0.f;
}

// ---------------- persistent cooperative loop ----------------
// PhaseA(t) = attn-gates GEMV(t) [WGs 0-111] || dec-gates GEMV(t-1) [112-239]
// PhaseB(t) = attention(t)+ctx(t) [0-31] || dec_cell(t-1) [32-63] || x-copy(t+1) [64-79]
__global__ void __launch_bounds__(512, 1) k_loop(Args a) {
  __shared__ SharedU sh;
  float* ws = a.ws;
  uintT* ctrs = (uintT*)(ws + WS_CTR);
  const ushortT* watb = (const ushortT*)(ws + WS_WATB);
  const ushortT* wdtb = (const ushortT*)(ws + WS_WDTB);
  const int wg = blockIdx.x;
  const int tid = threadIdx.x;
  uintT ph = 0;

  for (int t = 0; t <= cNSTEP; ++t) {
    const float* xa = ws + WS_XA + (size_t)(t & 1) * cB * cKA;
    float* xa2 = ws + WS_XA + (size_t)((t + 1) & 1) * cB * cKA;
    // ---- Phase A ----
    if (wg < 112) {
      if (t < cNSTEP) {
        const int s = wg >> 3, cb = wg & 7;
        gemv4<128, cNSA>(watb, xa, cKA, s * 128, ws + WS_GA, cb, s, sh.xs);
      }
    } else if (wg < 240) {
      if (t >= 1) {
        const int i = wg - 112, s = i >> 3, cb = i & 7;
        gemv4<160, cNSD>(wdtb, ws + WS_XD, cKD, s * 160, ws + WS_GD, cb, s, sh.xs);
      }
    }
    ++ph; gbar(ctrs, ph);
    // ---- Phase B ----
    if (wg < 32) {
      if (t < cNSTEP) attn_wg(a, ws, wg, t, xa2, sh);
    } else if (wg < 64) {
      if (t >= 1) dec_cell(a, ws, wg - 32, t - 1);
    } else if (wg < 80) {
      if (t + 1 < cNSTEP) {
        const int i = (wg - 64) * 512 + tid;   // 8192 = B*PRE
        const int b = i >> 8, j = i & 255;
        st_sc(xa2 + (size_t)b * cKA + j,
              ws[WS_XPRE + ((size_t)(t + 1) * cB + b) * cPRE + j]);
      }
    }
    ++ph; gbar(ctrs, ph);
  }
  mel_proj(a, ws, sh);
}

// ---------------- host ----------------
extern "C" void kernel_launch(void* const* d_in, const int* in_sizes, int n_in,
                              void* d_out, int out_size, void* d_ws, size_t ws_size,
                              hipStream_t stream) {
  (void)in_sizes; (void)n_in; (void)out_size;
  Args a;
  a.enc = (const float*)d_in[0];
  a.inputs = (const float*)d_in[1];
  a.mlen = (const int*)d_in[2];
  a.W1 = (const float*)d_in[3];  a.b1 = (const float*)d_in[4];
  a.W2 = (const float*)d_in[5];  a.b2 = (const float*)d_in[6];
  a.Wm = (const float*)d_in[7];
  a.Wih_a = (const float*)d_in[8];  a.Whh_a = (const float*)d_in[9];
  a.bih_a = (const float*)d_in[10]; a.bhh_a = (const float*)d_in[11];
  a.Wq = (const float*)d_in[12];
  a.conv_w = (const float*)d_in[13]; a.conv_b = (const float*)d_in[14];
  a.WL = (const float*)d_in[15];     a.v = (const float*)d_in[16];
  a.Wih_d = (const float*)d_in[17];  a.Whh_d = (const float*)d_in[18];
  a.bih_d = (const float*)d_in[19];  a.bhh_d = (const float*)d_in[20];
  a.Wmel = (const float*)d_in[21];   a.bmel = (const float*)d_in[22];
  a.Wstop = (const float*)d_in[23];  a.bstop = (const float*)d_in[24];
  a.out = (float*)d_out;
  a.ws = (float*)d_ws;

  if (ws_size < WS_TOTAL * sizeof(float)) {
    fprintf(stderr, "kernel_launch: ws too small: need %zu bytes, have %zu\n",
            WS_TOTAL * sizeof(float), ws_size);
    return;
  }

  float* ws = a.ws;
  ushortT* watb = (ushortT*)(ws + WS_WATB);
  ushortT* wdtb = (ushortT*)(ws + WS_WDTB);
  k_transpose_b16<<<dim3((768 / 64) * (4096 / 64)), dim3(256), 0, stream>>>(
      a.Wih_a, watb, 4096, 768, cNG);
  k_transpose_b16<<<dim3((1024 / 64) * (4096 / 64)), dim3(256), 0, stream>>>(
      a.Whh_a, watb + (size_t)768 * cNG, 4096, 1024, cNG);
  k_transpose_b16<<<dim3((1536 / 64) * (4096 / 64)), dim3(256), 0, stream>>>(
      a.Wih_d, wdtb, 4096, 1536, cNG);
  k_transpose_b16<<<dim3((1024 / 64) * (4096 / 64)), dim3(256), 0, stream>>>(
      a.Whh_d, wdtb + (size_t)1536 * cNG, 4096, 1024, cNG);
  k_transpose<<<dim3((1024 / 64) * (128 / 64)), dim3(256), 0, stream>>>(
      a.Wq, ws + WS_WQT, 128, 1024, cAD);
  k_transpose<<<dim3((512 / 64) * (128 / 64)), dim3(256), 0, stream>>>(
      a.Wm, ws + WS_WMTR, 128, 512, cAD);

  k_prep_small<<<dim3((cKM * cNMP + 255) / 256), dim3(256), 0, stream>>>(a);
  k_prenet1<<<dim3(8000), dim3(256), 0, stream>>>(a);
  k_prenet2<<<dim3(8000), dim3(256), 0, stream>>>(a);
  k_pm<<<dim3(4096), dim3(256), 0, stream>>>(a);
  k_init<<<dim3(288), dim3(256), 0, stream>>>(a);

  void* params[] = { (void*)&a };
  hipError_t err = hipLaunchCooperativeKernel((const void*)k_loop, dim3(256), dim3(512),
                                              params, 0, stream);
  if (err != hipSuccess) {
    fprintf(stderr, "kernel_launch: cooperative launch failed: %s\n",
            hipGetErrorString(err));
  }
}